// Round 3
// baseline (1937.845 us; speedup 1.0000x reference)
//
#include <hip/hip_runtime.h>
#include <hip/hip_bf16.h>
#include <cstdint>
#include <cstddef>

#define NN 20000
#define NE 640000
#define NF 64
#define HD 256
#define NL 4
#define HTS 640   // hT row stride in shorts: 1280 B = 5x256 B (destaggers HBM channels)
#define EB 32     // edges per block in edge_k (halved: frees regs, +occupancy)

typedef __attribute__((ext_vector_type(8))) short short8;
typedef __attribute__((ext_vector_type(4))) float f32x4;
typedef __attribute__((ext_vector_type(2))) float f32x2;

__device__ __forceinline__ float bf2f(unsigned short u){
  union { unsigned int i; float f; } x; x.i = ((unsigned int)u) << 16; return x.f;
}
__device__ __forceinline__ unsigned short f2bf(float f){
  union { float f; unsigned int i; } x; x.f = f;
  unsigned int r = x.i + 0x7FFFu + ((x.i >> 16) & 1u);   // RNE
  return (unsigned short)(r >> 16);
}
// packed 2xf32 -> 2xbf16 (v_cvt_pk_bf16_f32 on gfx950, RNE)
__device__ __forceinline__ unsigned int pk2bf(float a, float b){
  union { __hip_bfloat162 h; unsigned int u; } cv;
  cv.h = __float22bfloat162_rn(float2{a, b});
  return cv.u;
}
// silu via guaranteed-native v_exp_f32 + v_rcp_f32
__device__ __forceinline__ float silu_f(float v){
  float e = __builtin_amdgcn_exp2f(v * -1.442695041f);
  return v * __builtin_amdgcn_rcpf(1.0f + e);
}
// packed silu on 2 lanes: pk mul/add around the 2 scalar trans ops
__device__ __forceinline__ f32x2 silu2(f32x2 v){
  f32x2 t = v * (f32x2){-1.442695041f, -1.442695041f};   // v_pk_mul_f32
  f32x2 e = (f32x2){__builtin_amdgcn_exp2f(t.x), __builtin_amdgcn_exp2f(t.y)};
  f32x2 d = e + (f32x2){1.0f, 1.0f};                      // v_pk_add_f32
  f32x2 r = (f32x2){__builtin_amdgcn_rcpf(d.x), __builtin_amdgcn_rcpf(d.y)};
  return v * r;                                           // v_pk_mul_f32
}
__device__ __forceinline__ void async16(const void* g, void* l){
  __builtin_amdgcn_global_load_lds(
      (const __attribute__((address_space(1))) unsigned int*)g,
      (__attribute__((address_space(3))) unsigned int*)l, 16, 0, 0);
}

// ---------------- prep_small: weight transposes -> bf16, b1e (513-block slices) -------
__global__ __launch_bounds__(256) void prep_small(
    const float* __restrict__ w_in, const float* __restrict__ w_out,
    const float* __restrict__ ew1, const float* __restrict__ ew2,
    const float* __restrict__ nw1, const float* __restrict__ nw2,
    const float* __restrict__ eb1,
    unsigned short* __restrict__ w_in_t, unsigned short* __restrict__ w_out_t,
    unsigned short* __restrict__ ew1cat, float* __restrict__ w1r,
    float* __restrict__ b1e,
    unsigned short* __restrict__ ew2t, unsigned short* __restrict__ nw1t,
    unsigned short* __restrict__ nw2t)
{
  const int s = blockIdx.y;
  const int tid = blockIdx.x * 256 + threadIdx.x;
  if (s == 18) {
    if (tid < NL * 512) {
      int l = tid >> 9, c = tid & 511;
      b1e[tid] = (c < 256) ? eb1[l * HD + c] : 0.0f;
    }
    return;
  }
  if (s >= 2 && s < 6) {
    int l = s - 2;
    if (tid >= 513 * HD) return;
    int k = tid / HD, n = tid - k * HD;
    float v = ew1[(size_t)l * 513 * HD + tid];
    if (k == 512) { w1r[l * HD + n] = v; return; }
    unsigned short* dst = ew1cat + (size_t)l * 512 * 256;
    if (k < 256) dst[(size_t)n * 256 + k] = f2bf(v);
    else         dst[(size_t)(256 + n) * 256 + (k - 256)] = f2bf(v);
    return;
  }
  const float* src; unsigned short* dst; int K, N;
  if (s == 0)      { src = w_in;  dst = w_in_t;  K = NF;   N = HD; }
  else if (s == 1) { src = w_out; dst = w_out_t; K = HD;   N = NF; }
  else if (s < 10) { int l = s-6;  src = ew2 + (size_t)l*HD*HD;   dst = ew2t + (size_t)l*HD*HD;  K = HD;   N = HD; }
  else if (s < 14) { int l = s-10; src = nw1 + (size_t)l*2*HD*HD; dst = nw1t + (size_t)l*HD*512; K = 2*HD; N = HD; }
  else             { int l = s-14; src = nw2 + (size_t)l*HD*HD;   dst = nw2t + (size_t)l*HD*HD;  K = HD;   N = HD; }
  if (tid >= K * N) return;
  int k = tid / N, n = tid - k * N;
  dst[(size_t)n * K + k] = f2bf(src[tid]);
}

// ---------------- prep_big: h->bf16, radial ----------------
__global__ __launch_bounds__(256) void prep_big(
    const float* __restrict__ h_in, const float* __restrict__ cd,
    unsigned short* __restrict__ hb_in, float* __restrict__ radial)
{
  const int s = blockIdx.y;
  const int tid = blockIdx.x * 256 + threadIdx.x;
  if (s == 0) {
    if (tid < NN * NF) hb_in[tid] = f2bf(h_in[tid]);
  } else {
    if (tid < NE) {
      float x = cd[tid*3+0], y = cd[tid*3+1], z = cd[tid*3+2];
      radial[tid] = x*x + y*y + z*z;
    }
  }
}

// ---------------- counting sort of edges by row ----------------
__global__ __launch_bounds__(256) void hist_k(const int* __restrict__ erow, int* __restrict__ hist){
  int e = blockIdx.x * 256 + threadIdx.x;
  if (e < NE){
    unsigned r = (unsigned)erow[e]; if (r >= NN) r = 0;
    atomicAdd(&hist[r], 1);
  }
}

__global__ __launch_bounds__(256) void scan_k(const int* __restrict__ hist,
                                              int* __restrict__ starts, int* __restrict__ cursor){
  __shared__ int part[256];
  const int t = threadIdx.x;
  const int CH = 79;
  int lo = t * CH, hi = lo + CH; if (hi > NN) hi = NN; if (lo > NN) lo = NN;
  int s = 0;
  for (int i = lo; i < hi; ++i) s += hist[i];
  part[t] = s; __syncthreads();
  for (int off = 1; off < 256; off <<= 1){
    int v = (t >= off) ? part[t - off] : 0;
    __syncthreads();
    part[t] += v;
    __syncthreads();
  }
  int base = (t == 0) ? 0 : part[t - 1];
  for (int i = lo; i < hi; ++i){ starts[i] = base; cursor[i] = base; base += hist[i]; }
  if (t == 255) starts[NN] = part[255];
}

// scatter materializes (row,col) pairs and re-sorted radial at the sorted slot
__global__ __launch_bounds__(256) void scatter_k(const int* __restrict__ erow,
                                                 const int* __restrict__ ecol,
                                                 const float* __restrict__ radial,
                                                 int* __restrict__ cursor,
                                                 int* __restrict__ rowcol,
                                                 float* __restrict__ radial_s){
  int e = blockIdx.x * 256 + threadIdx.x;
  if (e < NE){
    unsigned r = (unsigned)erow[e]; if (r >= NN) r = 0;
    unsigned c = (unsigned)ecol[e]; if (c >= NN) c = 0;
    int pos = atomicAdd(&cursor[r], 1);
    rowcol[2*pos]   = (int)r;
    rowcol[2*pos+1] = (int)c;
    radial_s[pos] = radial[e];
  }
}

// ---------------- generic 128x128 bf16 MFMA GEMM: out = [silu](A @ Wt^T + bias) ------
__global__ __launch_bounds__(256) void gemm_k(
    const unsigned short* __restrict__ Am, const unsigned short* __restrict__ Wt,
    const float* __restrict__ bias,
    unsigned short* __restrict__ outB, float* __restrict__ outF,
    unsigned short* __restrict__ outB2,
    int M, int N, int K, int lda, int ldc, int fuseSilu)
{
  __shared__ __align__(16) unsigned short As[128*32];
  __shared__ __align__(16) unsigned short Bs[128*32];
  const int t = threadIdx.x;
  const int lane = t & 63, wave = t >> 6;
  const int ln15 = lane & 15, q = lane >> 4;
  const int bm = blockIdx.x, bn = blockIdx.y;
  const int wm = wave >> 1, wn = wave & 1;

  f32x4 acc[4][4];
  #pragma unroll
  for (int i = 0; i < 4; ++i)
    #pragma unroll
    for (int j = 0; j < 4; ++j) acc[i][j] = (f32x4){0.f,0.f,0.f,0.f};

  const int sr = t >> 2;
  const int sc = (t & 3) * 8;
  int am0 = bm*128 + sr;      if (am0 > M-1) am0 = M-1;
  int am1 = bm*128 + 64 + sr; if (am1 > M-1) am1 = M-1;
  int an0 = bn*128 + sr;      if (an0 > N-1) an0 = N-1;
  int an1 = bn*128 + 64 + sr; if (an1 > N-1) an1 = N-1;
  const unsigned short* a0 = Am + (size_t)am0 * lda + sc;
  const unsigned short* a1 = Am + (size_t)am1 * lda + sc;
  const unsigned short* b0 = Wt + (size_t)an0 * K + sc;
  const unsigned short* b1 = Wt + (size_t)an1 * K + sc;

  const int nkt = K >> 5;
  for (int kt = 0; kt < nkt; ++kt) {
    const int k0 = kt * 32;
    async16(a0 + k0, &As[t*8]);
    async16(a1 + k0, &As[2048 + t*8]);
    async16(b0 + k0, &Bs[t*8]);
    async16(b1 + k0, &Bs[2048 + t*8]);
    __syncthreads();
    short8 fa[4], fb[4];
    #pragma unroll
    for (int i = 0; i < 4; ++i)
      fa[i] = *(const short8*)&As[(wm*64 + i*16 + ln15)*32 + q*8];
    #pragma unroll
    for (int j = 0; j < 4; ++j)
      fb[j] = *(const short8*)&Bs[(wn*64 + j*16 + ln15)*32 + q*8];
    #pragma unroll
    for (int i = 0; i < 4; ++i)
      #pragma unroll
      for (int j = 0; j < 4; ++j)
        acc[i][j] = __builtin_amdgcn_mfma_f32_16x16x32_bf16(fa[i], fb[j], acc[i][j], 0, 0, 0);
    __syncthreads();
  }

  #pragma unroll
  for (int i = 0; i < 4; ++i) {
    #pragma unroll
    for (int j = 0; j < 4; ++j) {
      const int n = bn*128 + wn*64 + j*16 + ln15;
      if (n >= N) continue;
      const float bv = bias ? bias[n] : 0.0f;
      #pragma unroll
      for (int r = 0; r < 4; ++r) {
        const int m = bm*128 + wm*64 + i*16 + q*4 + r;
        if (m >= M) continue;
        float v = acc[i][j][r] + bv;
        if (fuseSilu) v = silu_f(v);
        if (outB) {
          unsigned short b = f2bf(v);
          outB[(size_t)m * ldc + n] = b;
          if (outB2 && n < 256) outB2[(size_t)m * 512 + n] = b;
        }
        else outF[(size_t)m * ldc + n] = v;
      }
    }
  }
}

// ---------------- fused edge MLP + aggregation, 32-edge tile ----------------
// 256 threads = 4 waves; per block: m1[32][256] -> m2 = silu(m1@W2^T+b2) -> seg-reduce.
// Thread map: e = t&31 (edge), u = t>>5 (32-col chunk). acc2 = 32 regs (half of before)
// -> fits __launch_bounds__(256,5): 5 blocks/CU (20 waves) vs previous 4 blocks/16 waves.
__global__ __launch_bounds__(256, 5) void edge_k(
    const unsigned short* __restrict__ hT,   // [NN][HTS] bf16, cols 0..511 valid
    const int* __restrict__ rowcol,          // [NE][2] sorted (row,col)
    const float* __restrict__ radial_s,      // [NE] sorted radial
    const float* __restrict__ w1r,           // [256]
    const unsigned short* __restrict__ w2t,  // [256][256]
    const float* __restrict__ b2,
    float* __restrict__ agg)                  // [NN][256] fp32, pre-zeroed
{
  __shared__ __align__(16) unsigned short MBUF[8704];   // max(M1 8192, m2T 256*34)
  __shared__ int rowS[EB];
  unsigned short* M1  = MBUF;
  unsigned short* m2T = MBUF;

  const int t = threadIdx.x;
  const int lane = t & 63, wave = t >> 6;
  const int ln15 = lane & 15, q = lane >> 4;
  // chunked XCD swizzle: XCD k owns a contiguous 1/8 of sorted-edge space
  int blk = blockIdx.x;
  blk = (blk & 7) * ((int)gridDim.x >> 3) + (blk >> 3);
  const int e0 = blk * EB;
  const int e = t & 31;             // edge within block
  const int u = t >> 5;             // 32-col chunk
  const int s = (e >> 1) & 3;       // col-group swizzle for this M1 row
  const int xq = (q ^ ((ln15 >> 1) & 3)) * 8;

  // gather base: ONE coalesced load (lanes 0..31 contiguous int2)
  const int2 rc = *(const int2*)(rowcol + 2*(e0 + e));
  const float rad = radial_s[e0 + e];
  if (t < EB) rowS[t] = rc.x;       // e==t for t<32

  float bv2[4];
  #pragma unroll
  for (int j = 0; j < 4; ++j) bv2[j] = b2[wave*64 + j*16 + ln15];

  const unsigned short* hr = hT + (size_t)rc.x * HTS + u*32;
  const unsigned short* hc = hT + (size_t)rc.y * HTS + 256 + u*32;
  const float* w1g = w1r + u*32;    // per-thread w1 slice straight from L2 (no LDS, no barrier)

  // batch all 8 gather b128s (32 VGPRs) — pre-swizzled col groups so M1 stores are linear
  short8 va[4], vb[4];
  #pragma unroll
  for (int p = 0; p < 4; ++p) {
    const int g = (p ^ s) * 8;
    va[p] = *(const short8*)(hr + g);
    vb[p] = *(const short8*)(hc + g);
  }

  const unsigned short* w2row[4];
  #pragma unroll
  for (int j = 0; j < 4; ++j)
    w2row[j] = w2t + (size_t)(wave*64 + j*16 + ln15) * HD + q*8;

  // prologue: m1 = silu(hr + hc + rad*w1r) -> M1 kt-blocked [u][e][p*8]
  const f32x2 rad2 = (f32x2){rad, rad};
  #pragma unroll
  for (int p = 0; p < 4; ++p) {
    const int g = (p ^ s) * 8;
    f32x4 w0 = *(const f32x4*)(w1g + g);
    f32x4 w1v = *(const f32x4*)(w1g + g + 4);
    float wArr[8] = {w0[0], w0[1], w0[2], w0[3], w1v[0], w1v[1], w1v[2], w1v[3]};
    const unsigned int* ua = (const unsigned int*)&va[p];
    const unsigned int* ub = (const unsigned int*)&vb[p];
    union { unsigned int u[4]; short8 s8; } res;
    #pragma unroll
    for (int i2 = 0; i2 < 4; ++i2) {
      union { unsigned int i; float f; } alo, ahi, blo, bhi;
      alo.i = ua[i2] << 16; ahi.i = ua[i2] & 0xFFFF0000u;
      blo.i = ub[i2] << 16; bhi.i = ub[i2] & 0xFFFF0000u;
      f32x2 av = (f32x2){alo.f, ahi.f};
      f32x2 bv = (f32x2){blo.f, bhi.f};
      f32x2 wv = (f32x2){wArr[2*i2], wArr[2*i2+1]};
      f32x2 o = av + bv;
      o = o + rad2 * wv;
      f32x2 sv = silu2(o);
      res.u[i2] = pk2bf(sv.x, sv.y);
    }
    *(short8*)&M1[u*1024 + e*32 + p*8] = res.s8;
  }
  __syncthreads();

  // phase 2: K = 256 (M1 @ W2^T); fb direct from global (L2-resident w2t)
  f32x4 acc2[2][4];
  #pragma unroll
  for (int i = 0; i < 2; ++i)
    #pragma unroll
    for (int j = 0; j < 4; ++j) acc2[i][j] = (f32x4){0.f,0.f,0.f,0.f};

  __builtin_amdgcn_s_setprio(1);
  #pragma unroll
  for (int kt = 0; kt < 8; ++kt) {
    short8 fa[2], fb[4];
    #pragma unroll
    for (int j = 0; j < 4; ++j) fb[j] = *(const short8*)(w2row[j] + kt*32);
    #pragma unroll
    for (int i = 0; i < 2; ++i) fa[i] = *(const short8*)&M1[kt*1024 + (i*16 + ln15)*32 + xq];
    #pragma unroll
    for (int i = 0; i < 2; ++i)
      #pragma unroll
      for (int j = 0; j < 4; ++j)
        acc2[i][j] = __builtin_amdgcn_mfma_f32_16x16x32_bf16(fa[i], fb[j], acc2[i][j], 0, 0, 0);
  }
  __builtin_amdgcn_s_setprio(0);
  __syncthreads();

  // epilogue 2a: silu -> m2T[col][stride 34] in LDS (pk math)
  #pragma unroll
  for (int i = 0; i < 2; ++i) {
    #pragma unroll
    for (int j = 0; j < 4; ++j) {
      const int n = wave*64 + j*16 + ln15;
      const f32x2 b2v = (f32x2){bv2[j], bv2[j]};
      f32x2 s01 = (f32x2){acc2[i][j][0], acc2[i][j][1]} + b2v;
      f32x2 s23 = (f32x2){acc2[i][j][2], acc2[i][j][3]} + b2v;
      f32x2 r01 = silu2(s01);
      f32x2 r23 = silu2(s23);
      const int m = i*16 + q*4;
      *(unsigned int*)&m2T[n*34 + m]     = pk2bf(r01.x, r01.y);
      *(unsigned int*)&m2T[n*34 + m + 2] = pk2bf(r23.x, r23.y);
    }
  }
  __syncthreads();

  // epilogue 2b: per-column segmented reduction over 32 sorted edges
  {
    const int c = t;
    int cur = __builtin_amdgcn_readfirstlane(rowS[0]);
    float sacc = 0.f;
    #pragma unroll
    for (int m = 0; m < EB; m += 4) {
      unsigned int u0 = *(const unsigned int*)&m2T[c*34 + m];
      unsigned int u1 = *(const unsigned int*)&m2T[c*34 + m + 2];
      int n0 = __builtin_amdgcn_readfirstlane(rowS[m]);
      int n1 = __builtin_amdgcn_readfirstlane(rowS[m+1]);
      int n2 = __builtin_amdgcn_readfirstlane(rowS[m+2]);
      int n3 = __builtin_amdgcn_readfirstlane(rowS[m+3]);
      float f0 = bf2f((unsigned short)u0), f1 = bf2f((unsigned short)(u0 >> 16));
      float f2v = bf2f((unsigned short)u1), f3 = bf2f((unsigned short)(u1 >> 16));
      if (n0 != cur) { atomicAdd(&agg[(size_t)cur * HD + c], sacc); sacc = 0.f; cur = n0; }
      sacc += f0;
      if (n1 != cur) { atomicAdd(&agg[(size_t)cur * HD + c], sacc); sacc = 0.f; cur = n1; }
      sacc += f1;
      if (n2 != cur) { atomicAdd(&agg[(size_t)cur * HD + c], sacc); sacc = 0.f; cur = n2; }
      sacc += f2v;
      if (n3 != cur) { atomicAdd(&agg[(size_t)cur * HD + c], sacc); sacc = 0.f; cur = n3; }
      sacc += f3;
    }
    atomicAdd(&agg[(size_t)cur * HD + c], sacc);
  }
}

// ---------------- aggcvt: xcat[:,256:512] = bf16(agg); agg re-zeroed ----------------
__global__ __launch_bounds__(256) void aggcvt_k(
    float* __restrict__ agg, unsigned short* __restrict__ xcat)
{
  const int g = blockIdx.x * 256 + threadIdx.x;
  const int node = g >> 6;
  const int c = (g & 63) * 4;
  if (node >= NN) return;
  float4 a = *(const float4*)(agg + (size_t)node * HD + c);
  uint2 pk; pk.x = pk2bf(a.x, a.y); pk.y = pk2bf(a.z, a.w);
  *(uint2*)(xcat + (size_t)node * 2 * HD + HD + c) = pk;
  *(float4*)(agg + (size_t)node * HD + c) = float4{0.f, 0.f, 0.f, 0.f};
}

// ---------------- launch ----------------
extern "C" void kernel_launch(void* const* d_in, const int* in_sizes, int n_in,
                              void* d_out, int out_size, void* d_ws, size_t ws_size,
                              hipStream_t stream)
{
  (void)in_sizes; (void)n_in; (void)out_size; (void)ws_size;
  const float* h_in  = (const float*)d_in[0];
  const int*   ei    = (const int*)d_in[1];
  const float* cd    = (const float*)d_in[2];
  const float* w_in  = (const float*)d_in[3];
  const float* b_in  = (const float*)d_in[4];
  const float* w_out = (const float*)d_in[5];
  const float* b_out = (const float*)d_in[6];
  const float* ew1   = (const float*)d_in[7];
  const float* eb1   = (const float*)d_in[8];
  const float* ew2   = (const float*)d_in[9];
  const float* eb2   = (const float*)d_in[10];
  const float* nw1   = (const float*)d_in[11];
  const float* nb1   = (const float*)d_in[12];
  const float* nw2   = (const float*)d_in[13];
  const float* nb2   = (const float*)d_in[14];
  float* out = (float*)d_out;

  char* base = (char*)d_ws;
  size_t off = 0;
  auto WS = [&](size_t bytes) -> char* {
    char* p = base + off;
    off = (off + bytes + 255) & ~(size_t)255;
    return p;
  };
  float*          radial  = (float*)WS((size_t)NE * 4);
  unsigned short* hb_in   = (unsigned short*)WS((size_t)NN * NF * 2);
  unsigned short* hcur    = (unsigned short*)WS((size_t)NN * HD * 2);
  unsigned short* xcat    = (unsigned short*)WS((size_t)NN * 2 * HD * 2);
  float*          aggF    = (float*)WS((size_t)NN * HD * 4);
  unsigned short* hT      = (unsigned short*)WS((size_t)NN * HTS * 2);  // 25.6 MB bf16
  unsigned short* x1      = hT;   // alias: hT dead once edge_k done; x1 lives after
  unsigned short* w_in_t  = (unsigned short*)WS((size_t)NF * HD * 2);
  unsigned short* w_out_t = (unsigned short*)WS((size_t)NF * HD * 2);
  unsigned short* ew1cat  = (unsigned short*)WS((size_t)NL * 512 * 256 * 2);
  float*          w1r     = (float*)WS((size_t)NL * HD * 4);
  float*          b1e     = (float*)WS((size_t)NL * 512 * 4);
  unsigned short* ew2t    = (unsigned short*)WS((size_t)NL * HD * HD * 2);
  unsigned short* nw1t    = (unsigned short*)WS((size_t)NL * HD * 512 * 2);
  unsigned short* nw2t    = (unsigned short*)WS((size_t)NL * HD * HD * 2);
  int*            hist    = (int*)WS((size_t)NN * 4);
  int*            starts  = (int*)WS((size_t)(NN + 1) * 4);
  int*            cursor  = (int*)WS((size_t)NN * 4);
  int*            rowcol  = (int*)WS((size_t)NE * 2 * 4);
  float*          radial_s= (float*)WS((size_t)NE * 4);

  hipMemsetAsync(hist, 0, (size_t)NN * 4, stream);
  hipMemsetAsync(aggF, 0, (size_t)NN * HD * 4, stream);
  prep_small<<<dim3(513, 19), 256, 0, stream>>>(w_in, w_out, ew1, ew2, nw1, nw2, eb1,
      w_in_t, w_out_t, ew1cat, w1r, b1e, ew2t, nw1t, nw2t);
  prep_big<<<dim3(5000, 2), 256, 0, stream>>>(h_in, cd, hb_in, radial);
  hist_k<<<NE / 256, 256, 0, stream>>>(ei, hist);
  scan_k<<<1, 256, 0, stream>>>(hist, starts, cursor);
  scatter_k<<<NE / 256, 256, 0, stream>>>(ei, ei + NE, radial, cursor, rowcol, radial_s);

  // h = h_in @ w_in + b_in  (also writes xcat first half)
  gemm_k<<<dim3(157, 2), 256, 0, stream>>>(hb_in, w_in_t, b_in, hcur, nullptr, xcat,
      NN, HD, NF, NF, HD, 0);

  for (int l = 0; l < NL; ++l) {
    // node-level phase-1 table (bf16, destaggered stride): hT = hcur @ W1cat^T + b1e
    gemm_k<<<dim3(157, 4), 256, 0, stream>>>(hcur, ew1cat + (size_t)l * 512 * 256,
        b1e + (size_t)l * 512, hT, nullptr, nullptr, NN, 512, HD, HD, HTS, 0);
    edge_k<<<NE / EB, 256, 0, stream>>>(hT, rowcol, radial_s,
        w1r + l * HD, ew2t + (size_t)l * HD * HD, eb2 + l * HD, aggF);
    aggcvt_k<<<NN * 64 / 256, 256, 0, stream>>>(aggF, xcat);
    gemm_k<<<dim3(157, 2), 256, 0, stream>>>(xcat, nw1t + (size_t)l * HD * 512,
        nb1 + l * HD, x1, nullptr, nullptr, NN, HD, 2 * HD, 2 * HD, HD, 1);
    // nw2 writes hcur AND xcat first half for the next layer's concat
    gemm_k<<<dim3(157, 2), 256, 0, stream>>>(x1, nw2t + (size_t)l * HD * HD,
        nb2 + l * HD, hcur, nullptr, (l < NL-1) ? xcat : nullptr, NN, HD, HD, HD, HD, 0);
  }

  // out = h @ w_out + b_out  (fp32 output)
  gemm_k<<<dim3(157, 1), 256, 0, stream>>>(hcur, w_out_t, b_out, nullptr, out, nullptr,
      NN, NF, HD, HD, NF, 0);
}

// Round 4
// 1425.466 us; speedup vs baseline: 1.3594x; 1.3594x over previous
//
#include <hip/hip_runtime.h>
#include <hip/hip_bf16.h>
#include <cstdint>
#include <cstddef>

#define NN 20000
#define NE 640000
#define NF 64
#define HD 256
#define NL 4
#define HTS 640   // hT row stride in shorts: 1280 B = 5x256 B (destaggers HBM channels)

typedef __attribute__((ext_vector_type(8))) short short8;
typedef __attribute__((ext_vector_type(4))) float f32x4;
typedef __attribute__((ext_vector_type(2))) float f32x2;

__device__ __forceinline__ float bf2f(unsigned short u){
  union { unsigned int i; float f; } x; x.i = ((unsigned int)u) << 16; return x.f;
}
__device__ __forceinline__ unsigned short f2bf(float f){
  union { float f; unsigned int i; } x; x.f = f;
  unsigned int r = x.i + 0x7FFFu + ((x.i >> 16) & 1u);   // RNE
  return (unsigned short)(r >> 16);
}
// packed 2xf32 -> 2xbf16 (v_cvt_pk_bf16_f32 on gfx950, RNE)
__device__ __forceinline__ unsigned int pk2bf(float a, float b){
  union { __hip_bfloat162 h; unsigned int u; } cv;
  cv.h = __float22bfloat162_rn(float2{a, b});
  return cv.u;
}
// silu via guaranteed-native v_exp_f32 + v_rcp_f32
__device__ __forceinline__ float silu_f(float v){
  float e = __builtin_amdgcn_exp2f(v * -1.442695041f);
  return v * __builtin_amdgcn_rcpf(1.0f + e);
}
// packed silu on 2 lanes: pk mul/add around the 2 scalar trans ops
__device__ __forceinline__ f32x2 silu2(f32x2 v){
  f32x2 t = v * (f32x2){-1.442695041f, -1.442695041f};   // v_pk_mul_f32
  f32x2 e = (f32x2){__builtin_amdgcn_exp2f(t.x), __builtin_amdgcn_exp2f(t.y)};
  f32x2 d = e + (f32x2){1.0f, 1.0f};                      // v_pk_add_f32
  f32x2 r = (f32x2){__builtin_amdgcn_rcpf(d.x), __builtin_amdgcn_rcpf(d.y)};
  return v * r;                                           // v_pk_mul_f32
}
__device__ __forceinline__ void async16(const void* g, void* l){
  __builtin_amdgcn_global_load_lds(
      (const __attribute__((address_space(1))) unsigned int*)g,
      (__attribute__((address_space(3))) unsigned int*)l, 16, 0, 0);
}

// ---------------- prep_small: weight transposes -> bf16, b1e (513-block slices) -------
__global__ __launch_bounds__(256) void prep_small(
    const float* __restrict__ w_in, const float* __restrict__ w_out,
    const float* __restrict__ ew1, const float* __restrict__ ew2,
    const float* __restrict__ nw1, const float* __restrict__ nw2,
    const float* __restrict__ eb1,
    unsigned short* __restrict__ w_in_t, unsigned short* __restrict__ w_out_t,
    unsigned short* __restrict__ ew1cat, float* __restrict__ w1r,
    float* __restrict__ b1e,
    unsigned short* __restrict__ ew2t, unsigned short* __restrict__ nw1t,
    unsigned short* __restrict__ nw2t)
{
  const int s = blockIdx.y;
  const int tid = blockIdx.x * 256 + threadIdx.x;
  if (s == 18) {
    if (tid < NL * 512) {
      int l = tid >> 9, c = tid & 511;
      b1e[tid] = (c < 256) ? eb1[l * HD + c] : 0.0f;
    }
    return;
  }
  if (s >= 2 && s < 6) {
    int l = s - 2;
    if (tid >= 513 * HD) return;
    int k = tid / HD, n = tid - k * HD;
    float v = ew1[(size_t)l * 513 * HD + tid];
    if (k == 512) { w1r[l * HD + n] = v; return; }
    unsigned short* dst = ew1cat + (size_t)l * 512 * 256;
    if (k < 256) dst[(size_t)n * 256 + k] = f2bf(v);
    else         dst[(size_t)(256 + n) * 256 + (k - 256)] = f2bf(v);
    return;
  }
  const float* src; unsigned short* dst; int K, N;
  if (s == 0)      { src = w_in;  dst = w_in_t;  K = NF;   N = HD; }
  else if (s == 1) { src = w_out; dst = w_out_t; K = HD;   N = NF; }
  else if (s < 10) { int l = s-6;  src = ew2 + (size_t)l*HD*HD;   dst = ew2t + (size_t)l*HD*HD;  K = HD;   N = HD; }
  else if (s < 14) { int l = s-10; src = nw1 + (size_t)l*2*HD*HD; dst = nw1t + (size_t)l*HD*512; K = 2*HD; N = HD; }
  else             { int l = s-14; src = nw2 + (size_t)l*HD*HD;   dst = nw2t + (size_t)l*HD*HD;  K = HD;   N = HD; }
  if (tid >= K * N) return;
  int k = tid / N, n = tid - k * N;
  dst[(size_t)n * K + k] = f2bf(src[tid]);
}

// ---------------- prep_big: h->bf16, radial ----------------
__global__ __launch_bounds__(256) void prep_big(
    const float* __restrict__ h_in, const float* __restrict__ cd,
    unsigned short* __restrict__ hb_in, float* __restrict__ radial)
{
  const int s = blockIdx.y;
  const int tid = blockIdx.x * 256 + threadIdx.x;
  if (s == 0) {
    if (tid < NN * NF) hb_in[tid] = f2bf(h_in[tid]);
  } else {
    if (tid < NE) {
      float x = cd[tid*3+0], y = cd[tid*3+1], z = cd[tid*3+2];
      radial[tid] = x*x + y*y + z*z;
    }
  }
}

// ---------------- counting sort of edges by row ----------------
__global__ __launch_bounds__(256) void hist_k(const int* __restrict__ erow, int* __restrict__ hist){
  int e = blockIdx.x * 256 + threadIdx.x;
  if (e < NE){
    unsigned r = (unsigned)erow[e]; if (r >= NN) r = 0;
    atomicAdd(&hist[r], 1);
  }
}

__global__ __launch_bounds__(256) void scan_k(const int* __restrict__ hist,
                                              int* __restrict__ starts, int* __restrict__ cursor){
  __shared__ int part[256];
  const int t = threadIdx.x;
  const int CH = 79;
  int lo = t * CH, hi = lo + CH; if (hi > NN) hi = NN; if (lo > NN) lo = NN;
  int s = 0;
  for (int i = lo; i < hi; ++i) s += hist[i];
  part[t] = s; __syncthreads();
  for (int off = 1; off < 256; off <<= 1){
    int v = (t >= off) ? part[t - off] : 0;
    __syncthreads();
    part[t] += v;
    __syncthreads();
  }
  int base = (t == 0) ? 0 : part[t - 1];
  for (int i = lo; i < hi; ++i){ starts[i] = base; cursor[i] = base; base += hist[i]; }
  if (t == 255) starts[NN] = part[255];
}

// scatter materializes (row,col) pairs and re-sorted radial at the sorted slot
__global__ __launch_bounds__(256) void scatter_k(const int* __restrict__ erow,
                                                 const int* __restrict__ ecol,
                                                 const float* __restrict__ radial,
                                                 int* __restrict__ cursor,
                                                 int* __restrict__ rowcol,
                                                 float* __restrict__ radial_s){
  int e = blockIdx.x * 256 + threadIdx.x;
  if (e < NE){
    unsigned r = (unsigned)erow[e]; if (r >= NN) r = 0;
    unsigned c = (unsigned)ecol[e]; if (c >= NN) c = 0;
    int pos = atomicAdd(&cursor[r], 1);
    rowcol[2*pos]   = (int)r;
    rowcol[2*pos+1] = (int)c;
    radial_s[pos] = radial[e];
  }
}

// ---------------- generic 128x128 bf16 MFMA GEMM: out = [silu](A @ Wt^T + bias) ------
__global__ __launch_bounds__(256) void gemm_k(
    const unsigned short* __restrict__ Am, const unsigned short* __restrict__ Wt,
    const float* __restrict__ bias,
    unsigned short* __restrict__ outB, float* __restrict__ outF,
    unsigned short* __restrict__ outB2,
    int M, int N, int K, int lda, int ldc, int fuseSilu)
{
  __shared__ __align__(16) unsigned short As[128*32];
  __shared__ __align__(16) unsigned short Bs[128*32];
  const int t = threadIdx.x;
  const int lane = t & 63, wave = t >> 6;
  const int ln15 = lane & 15, q = lane >> 4;
  const int bm = blockIdx.x, bn = blockIdx.y;
  const int wm = wave >> 1, wn = wave & 1;

  f32x4 acc[4][4];
  #pragma unroll
  for (int i = 0; i < 4; ++i)
    #pragma unroll
    for (int j = 0; j < 4; ++j) acc[i][j] = (f32x4){0.f,0.f,0.f,0.f};

  const int sr = t >> 2;
  const int sc = (t & 3) * 8;
  int am0 = bm*128 + sr;      if (am0 > M-1) am0 = M-1;
  int am1 = bm*128 + 64 + sr; if (am1 > M-1) am1 = M-1;
  int an0 = bn*128 + sr;      if (an0 > N-1) an0 = N-1;
  int an1 = bn*128 + 64 + sr; if (an1 > N-1) an1 = N-1;
  const unsigned short* a0 = Am + (size_t)am0 * lda + sc;
  const unsigned short* a1 = Am + (size_t)am1 * lda + sc;
  const unsigned short* b0 = Wt + (size_t)an0 * K + sc;
  const unsigned short* b1 = Wt + (size_t)an1 * K + sc;

  const int nkt = K >> 5;
  for (int kt = 0; kt < nkt; ++kt) {
    const int k0 = kt * 32;
    async16(a0 + k0, &As[t*8]);
    async16(a1 + k0, &As[2048 + t*8]);
    async16(b0 + k0, &Bs[t*8]);
    async16(b1 + k0, &Bs[2048 + t*8]);
    __syncthreads();
    short8 fa[4], fb[4];
    #pragma unroll
    for (int i = 0; i < 4; ++i)
      fa[i] = *(const short8*)&As[(wm*64 + i*16 + ln15)*32 + q*8];
    #pragma unroll
    for (int j = 0; j < 4; ++j)
      fb[j] = *(const short8*)&Bs[(wn*64 + j*16 + ln15)*32 + q*8];
    #pragma unroll
    for (int i = 0; i < 4; ++i)
      #pragma unroll
      for (int j = 0; j < 4; ++j)
        acc[i][j] = __builtin_amdgcn_mfma_f32_16x16x32_bf16(fa[i], fb[j], acc[i][j], 0, 0, 0);
    __syncthreads();
  }

  #pragma unroll
  for (int i = 0; i < 4; ++i) {
    #pragma unroll
    for (int j = 0; j < 4; ++j) {
      const int n = bn*128 + wn*64 + j*16 + ln15;
      if (n >= N) continue;
      const float bv = bias ? bias[n] : 0.0f;
      #pragma unroll
      for (int r = 0; r < 4; ++r) {
        const int m = bm*128 + wm*64 + i*16 + q*4 + r;
        if (m >= M) continue;
        float v = acc[i][j][r] + bv;
        if (fuseSilu) v = silu_f(v);
        if (outB) {
          unsigned short b = f2bf(v);
          outB[(size_t)m * ldc + n] = b;
          if (outB2 && n < 256) outB2[(size_t)m * 512 + n] = b;
        }
        else outF[(size_t)m * ldc + n] = v;
      }
    }
  }
}

// ---------------- fused edge MLP + aggregation (64-edge tile, MFMA seg-sum) ----------
// m2T layout: [col][72 shorts], edge chunks of 8 XOR-swizzled: phys chunk = (m>>3)^(col&7)
__global__ __launch_bounds__(256, 4) void edge_k(
    const unsigned short* __restrict__ hT,   // [NN][HTS] bf16, cols 0..511 valid
    const int* __restrict__ rowcol,          // [NE][2] sorted (row,col)
    const float* __restrict__ radial_s,      // [NE] sorted radial
    const float* __restrict__ w1r,           // [256]
    const unsigned short* __restrict__ w2t,  // [256][256]
    const float* __restrict__ b2,
    float* __restrict__ agg)                  // [NN][256] fp32, pre-zeroed
{
  __shared__ __align__(16) unsigned short MBUF[18432];   // max(M1 32KB, m2T 256*72*2B)
  __shared__ __align__(16) int rowS[64];
  __shared__ float w1rS[256];
  unsigned short* M1  = MBUF;
  unsigned short* m2T = MBUF;

  const int t = threadIdx.x;
  const int lane = t & 63, wave = t >> 6;
  const int ln15 = lane & 15, q = lane >> 4;
  // chunked XCD swizzle: XCD k owns a contiguous 1/8 of sorted-edge space (hr L2 reuse)
  int blk = blockIdx.x;
  blk = (blk & 7) * ((int)gridDim.x >> 3) + (blk >> 3);
  const int e0 = blk * 64;
  const int sr = t >> 2;
  const int sc_swz = (((t & 3) ^ ((sr >> 1) & 3))) * 8;
  const int xq = ((q ^ ((ln15 >> 1) & 3))) * 8;

  // early small loads (before the 16 gathers: vmcnt retires in issue order)
  const int2 rc = *(const int2*)(rowcol + 2*(e0 + sr));   // gather base (1 load)
  int rowv = 0;
  if (t < 64) rowv = rowcol[2*(e0 + t)];
  const float w1v = w1r[t];
  const float rad = radial_s[e0 + sr];

  float bv2[4];
  #pragma unroll
  for (int j = 0; j < 4; ++j) bv2[j] = b2[wave*64 + j*16 + ln15];

  const unsigned short* hr = hT + (size_t)rc.x * HTS + sc_swz;
  const unsigned short* hc = hT + (size_t)rc.y * HTS + 256 + sc_swz;

  // batch all 16 gather b128s into registers, interleaved
  short8 va[8], vb[8];
  #pragma unroll
  for (int ch = 0; ch < 8; ++ch) {
    va[ch] = *(const short8*)(hr + ch*32);
    vb[ch] = *(const short8*)(hc + ch*32);
  }

  if (t < 64) rowS[t] = rowv;
  w1rS[t] = w1v;

  const unsigned short* w2row[4];
  #pragma unroll
  for (int j = 0; j < 4; ++j)
    w2row[j] = w2t + (size_t)(wave*64 + j*16 + ln15) * HD + q*8;

  __syncthreads();

  // prologue: m1 = silu(hr + hc + rad*w1r) -> M1 (kt-blocked, swizzled), b128 stores
  const f32x2 rad2 = (f32x2){rad, rad};
  #pragma unroll
  for (int ch = 0; ch < 8; ++ch) {
    const int c0 = ch*32 + sc_swz;
    const unsigned int* ua = (const unsigned int*)&va[ch];
    const unsigned int* ub = (const unsigned int*)&vb[ch];
    union { unsigned int u[4]; short8 s; } res;
    #pragma unroll
    for (int i = 0; i < 4; ++i) {
      union { unsigned int i; float f; } alo, ahi, blo, bhi;
      alo.i = ua[i] << 16; ahi.i = ua[i] & 0xFFFF0000u;
      blo.i = ub[i] << 16; bhi.i = ub[i] & 0xFFFF0000u;
      f32x2 av = (f32x2){alo.f, ahi.f};
      f32x2 bv = (f32x2){blo.f, bhi.f};
      f32x2 wv = *(const f32x2*)&w1rS[c0 + 2*i];
      f32x2 o = av + bv;
      o = o + rad2 * wv;            // pk fma
      f32x2 sv = silu2(o);
      res.u[i] = pk2bf(sv.x, sv.y);
    }
    *(short8*)&M1[ch*2048 + sr*32 + (t & 3)*8] = res.s;
  }
  __syncthreads();

  // phase 2: K = 256 (M1 @ W2^T); fb direct from global (L2-resident w2t)
  f32x4 acc2[4][4];
  #pragma unroll
  for (int i = 0; i < 4; ++i)
    #pragma unroll
    for (int j = 0; j < 4; ++j) acc2[i][j] = (f32x4){0.f,0.f,0.f,0.f};

  __builtin_amdgcn_s_setprio(1);
  #pragma unroll
  for (int kt = 0; kt < 8; ++kt) {
    short8 fa[4], fb[4];
    #pragma unroll
    for (int j = 0; j < 4; ++j) fb[j] = *(const short8*)(w2row[j] + kt*32);
    #pragma unroll
    for (int i = 0; i < 4; ++i) fa[i] = *(const short8*)&M1[kt*2048 + (i*16 + ln15)*32 + xq];
    #pragma unroll
    for (int i = 0; i < 4; ++i)
      #pragma unroll
      for (int j = 0; j < 4; ++j)
        acc2[i][j] = __builtin_amdgcn_mfma_f32_16x16x32_bf16(fa[i], fb[j], acc2[i][j], 0, 0, 0);
  }
  __builtin_amdgcn_s_setprio(0);
  __syncthreads();

  // epilogue 2a: silu -> m2T[col][edge] (stride 72, XOR-chunked) in LDS (pk math)
  #pragma unroll
  for (int i = 0; i < 4; ++i) {
    #pragma unroll
    for (int j = 0; j < 4; ++j) {
      const int n = wave*64 + j*16 + ln15;
      const f32x2 b2v = (f32x2){bv2[j], bv2[j]};
      f32x2 s01 = (f32x2){acc2[i][j][0], acc2[i][j][1]} + b2v;
      f32x2 s23 = (f32x2){acc2[i][j][2], acc2[i][j][3]} + b2v;
      f32x2 r01 = silu2(s01);
      f32x2 r23 = silu2(s23);
      const int m = i*16 + q*4;
      const int base = n*72 + (((m >> 3) ^ (n & 7)) << 3) + (m & 7);
      *(unsigned int*)&m2T[base]     = pk2bf(r01.x, r01.y);
      *(unsigned int*)&m2T[base + 2] = pk2bf(r23.x, r23.y);
    }
  }
  __syncthreads();

  // epilogue 2b: segment sum. Typical: block spans <=16 rows (avg degree 32 -> ~3)
  // => MFMA path: segsum[16][256] = sel[16][64] @ m2[64][256], 2 MFMAs x 4 col-tiles/wave.
  const int seg0 = __builtin_amdgcn_readfirstlane(rowS[0]);
  const int rend = __builtin_amdgcn_readfirstlane(rowS[63]);
  const int span = rend - seg0 + 1;
  if (span <= 16) {
    // selector A-frags: lane holds sel[seg=ln15][edge = kt2*32 + q*8 + i]
    const int tgt = seg0 + ln15;
    short8 sf[2];
    #pragma unroll
    for (int kt2 = 0; kt2 < 2; ++kt2) {
      const int* rp = &rowS[kt2*32 + q*8];
      short8 s8;
      #pragma unroll
      for (int i = 0; i < 8; ++i)
        s8[i] = (short)((rp[i] == tgt) ? 0x3F80 : 0);
      sf[kt2] = s8;
    }
    #pragma unroll
    for (int ct = 0; ct < 4; ++ct) {
      const int col = wave*64 + ct*16 + ln15;
      f32x4 a3 = (f32x4){0.f,0.f,0.f,0.f};
      #pragma unroll
      for (int kt2 = 0; kt2 < 2; ++kt2) {
        const int chunk = (kt2*4 + q) ^ (col & 7);
        short8 bf = *(const short8*)&m2T[col*72 + chunk*8];
        a3 = __builtin_amdgcn_mfma_f32_16x16x32_bf16(sf[kt2], bf, a3, 0, 0, 0);
      }
      #pragma unroll
      for (int r = 0; r < 4; ++r) {
        const int sgi = q*4 + r;
        const float v = a3[r];
        if (sgi < span && v != 0.0f)
          atomicAdd(&agg[(size_t)(seg0 + sgi) * HD + col], v);
      }
    }
  } else {
    // rare fallback: serial per-column segmented scan (un-swizzles chunks)
    const int c = t;
    int cur = seg0;
    float s = 0.f;
    #pragma unroll
    for (int m = 0; m < 64; m += 4) {
      const int base = c*72 + (((m >> 3) ^ (c & 7)) << 3) + (m & 7);
      unsigned int u0 = *(const unsigned int*)&m2T[base];
      unsigned int u1 = *(const unsigned int*)&m2T[base + 2];
      int n0 = __builtin_amdgcn_readfirstlane(rowS[m]);
      int n1 = __builtin_amdgcn_readfirstlane(rowS[m+1]);
      int n2 = __builtin_amdgcn_readfirstlane(rowS[m+2]);
      int n3 = __builtin_amdgcn_readfirstlane(rowS[m+3]);
      float f0 = bf2f((unsigned short)u0), f1 = bf2f((unsigned short)(u0 >> 16));
      float f2v = bf2f((unsigned short)u1), f3 = bf2f((unsigned short)(u1 >> 16));
      if (n0 != cur) { atomicAdd(&agg[(size_t)cur * HD + c], s); s = 0.f; cur = n0; }
      s += f0;
      if (n1 != cur) { atomicAdd(&agg[(size_t)cur * HD + c], s); s = 0.f; cur = n1; }
      s += f1;
      if (n2 != cur) { atomicAdd(&agg[(size_t)cur * HD + c], s); s = 0.f; cur = n2; }
      s += f2v;
      if (n3 != cur) { atomicAdd(&agg[(size_t)cur * HD + c], s); s = 0.f; cur = n3; }
      s += f3;
    }
    atomicAdd(&agg[(size_t)cur * HD + c], s);
  }
}

// ---------------- aggcvt: xcat[:,256:512] = bf16(agg); agg re-zeroed ----------------
__global__ __launch_bounds__(256) void aggcvt_k(
    float* __restrict__ agg, unsigned short* __restrict__ xcat)
{
  const int g = blockIdx.x * 256 + threadIdx.x;
  const int node = g >> 6;
  const int c = (g & 63) * 4;
  if (node >= NN) return;
  float4 a = *(const float4*)(agg + (size_t)node * HD + c);
  uint2 pk; pk.x = pk2bf(a.x, a.y); pk.y = pk2bf(a.z, a.w);
  *(uint2*)(xcat + (size_t)node * 2 * HD + HD + c) = pk;
  *(float4*)(agg + (size_t)node * HD + c) = float4{0.f, 0.f, 0.f, 0.f};
}

// ---------------- launch ----------------
extern "C" void kernel_launch(void* const* d_in, const int* in_sizes, int n_in,
                              void* d_out, int out_size, void* d_ws, size_t ws_size,
                              hipStream_t stream)
{
  (void)in_sizes; (void)n_in; (void)out_size; (void)ws_size;
  const float* h_in  = (const float*)d_in[0];
  const int*   ei    = (const int*)d_in[1];
  const float* cd    = (const float*)d_in[2];
  const float* w_in  = (const float*)d_in[3];
  const float* b_in  = (const float*)d_in[4];
  const float* w_out = (const float*)d_in[5];
  const float* b_out = (const float*)d_in[6];
  const float* ew1   = (const float*)d_in[7];
  const float* eb1   = (const float*)d_in[8];
  const float* ew2   = (const float*)d_in[9];
  const float* eb2   = (const float*)d_in[10];
  const float* nw1   = (const float*)d_in[11];
  const float* nb1   = (const float*)d_in[12];
  const float* nw2   = (const float*)d_in[13];
  const float* nb2   = (const float*)d_in[14];
  float* out = (float*)d_out;

  char* base = (char*)d_ws;
  size_t off = 0;
  auto WS = [&](size_t bytes) -> char* {
    char* p = base + off;
    off = (off + bytes + 255) & ~(size_t)255;
    return p;
  };
  float*          radial  = (float*)WS((size_t)NE * 4);
  unsigned short* hb_in   = (unsigned short*)WS((size_t)NN * NF * 2);
  unsigned short* hcur    = (unsigned short*)WS((size_t)NN * HD * 2);
  unsigned short* xcat    = (unsigned short*)WS((size_t)NN * 2 * HD * 2);
  float*          aggF    = (float*)WS((size_t)NN * HD * 4);
  unsigned short* hT      = (unsigned short*)WS((size_t)NN * HTS * 2);  // 25.6 MB bf16
  unsigned short* x1      = hT;   // alias: hT dead once edge_k done; x1 lives after
  unsigned short* w_in_t  = (unsigned short*)WS((size_t)NF * HD * 2);
  unsigned short* w_out_t = (unsigned short*)WS((size_t)NF * HD * 2);
  unsigned short* ew1cat  = (unsigned short*)WS((size_t)NL * 512 * 256 * 2);
  float*          w1r     = (float*)WS((size_t)NL * HD * 4);
  float*          b1e     = (float*)WS((size_t)NL * 512 * 4);
  unsigned short* ew2t    = (unsigned short*)WS((size_t)NL * HD * HD * 2);
  unsigned short* nw1t    = (unsigned short*)WS((size_t)NL * HD * 512 * 2);
  unsigned short* nw2t    = (unsigned short*)WS((size_t)NL * HD * HD * 2);
  int*            hist    = (int*)WS((size_t)NN * 4);
  int*            starts  = (int*)WS((size_t)(NN + 1) * 4);
  int*            cursor  = (int*)WS((size_t)NN * 4);
  int*            rowcol  = (int*)WS((size_t)NE * 2 * 4);
  float*          radial_s= (float*)WS((size_t)NE * 4);

  hipMemsetAsync(hist, 0, (size_t)NN * 4, stream);
  hipMemsetAsync(aggF, 0, (size_t)NN * HD * 4, stream);
  prep_small<<<dim3(513, 19), 256, 0, stream>>>(w_in, w_out, ew1, ew2, nw1, nw2, eb1,
      w_in_t, w_out_t, ew1cat, w1r, b1e, ew2t, nw1t, nw2t);
  prep_big<<<dim3(5000, 2), 256, 0, stream>>>(h_in, cd, hb_in, radial);
  hist_k<<<NE / 256, 256, 0, stream>>>(ei, hist);
  scan_k<<<1, 256, 0, stream>>>(hist, starts, cursor);
  scatter_k<<<NE / 256, 256, 0, stream>>>(ei, ei + NE, radial, cursor, rowcol, radial_s);

  // h = h_in @ w_in + b_in  (also writes xcat first half)
  gemm_k<<<dim3(157, 2), 256, 0, stream>>>(hb_in, w_in_t, b_in, hcur, nullptr, xcat,
      NN, HD, NF, NF, HD, 0);

  for (int l = 0; l < NL; ++l) {
    // node-level phase-1 table (bf16, destaggered stride): hT = hcur @ W1cat^T + b1e
    gemm_k<<<dim3(157, 4), 256, 0, stream>>>(hcur, ew1cat + (size_t)l * 512 * 256,
        b1e + (size_t)l * 512, hT, nullptr, nullptr, NN, 512, HD, HD, HTS, 0);
    edge_k<<<NE / 64, 256, 0, stream>>>(hT, rowcol, radial_s,
        w1r + l * HD, ew2t + (size_t)l * HD * HD, eb2 + l * HD, aggF);
    aggcvt_k<<<NN * 64 / 256, 256, 0, stream>>>(aggF, xcat);
    gemm_k<<<dim3(157, 2), 256, 0, stream>>>(xcat, nw1t + (size_t)l * HD * 512,
        nb1 + l * HD, x1, nullptr, nullptr, NN, HD, 2 * HD, 2 * HD, HD, 1);
    // nw2 writes hcur AND xcat first half for the next layer's concat
    gemm_k<<<dim3(157, 2), 256, 0, stream>>>(x1, nw2t + (size_t)l * HD * HD,
        nb2 + l * HD, hcur, nullptr, (l < NL-1) ? xcat : nullptr, NN, HD, HD, HD, HD, 0);
  }

  // out = h @ w_out + b_out  (fp32 output)
  gemm_k<<<dim3(157, 1), 256, 0, stream>>>(hcur, w_out_t, b_out, nullptr, out, nullptr,
      NN, NF, HD, HD, NF, 0);
}

// Round 5
// 1232.393 us; speedup vs baseline: 1.5724x; 1.1567x over previous
//
#include <hip/hip_runtime.h>
#include <hip/hip_bf16.h>
#include <cstdint>
#include <cstddef>

#define NN 20000
#define NE 640000
#define NF 64
#define HD 256
#define NL 4
#define HTS 640   // hT row stride in shorts: 1280 B = 5x256 B (destaggers HBM channels)

typedef __attribute__((ext_vector_type(8))) short short8;
typedef __attribute__((ext_vector_type(4))) float f32x4;
typedef __attribute__((ext_vector_type(2))) float f32x2;

__device__ __forceinline__ float bf2f(unsigned short u){
  union { unsigned int i; float f; } x; x.i = ((unsigned int)u) << 16; return x.f;
}
__device__ __forceinline__ unsigned short f2bf(float f){
  union { float f; unsigned int i; } x; x.f = f;
  unsigned int r = x.i + 0x7FFFu + ((x.i >> 16) & 1u);   // RNE
  return (unsigned short)(r >> 16);
}
// packed 2xf32 -> 2xbf16 (v_cvt_pk_bf16_f32 on gfx950, RNE)
__device__ __forceinline__ unsigned int pk2bf(float a, float b){
  union { __hip_bfloat162 h; unsigned int u; } cv;
  cv.h = __float22bfloat162_rn(float2{a, b});
  return cv.u;
}
// silu via guaranteed-native v_exp_f32 + v_rcp_f32
__device__ __forceinline__ float silu_f(float v){
  float e = __builtin_amdgcn_exp2f(v * -1.442695041f);
  return v * __builtin_amdgcn_rcpf(1.0f + e);
}
// packed silu on 2 lanes: pk mul/add around the 2 scalar trans ops
__device__ __forceinline__ f32x2 silu2(f32x2 v){
  f32x2 t = v * (f32x2){-1.442695041f, -1.442695041f};   // v_pk_mul_f32
  f32x2 e = (f32x2){__builtin_amdgcn_exp2f(t.x), __builtin_amdgcn_exp2f(t.y)};
  f32x2 d = e + (f32x2){1.0f, 1.0f};                      // v_pk_add_f32
  f32x2 r = (f32x2){__builtin_amdgcn_rcpf(d.x), __builtin_amdgcn_rcpf(d.y)};
  return v * r;                                           // v_pk_mul_f32
}
__device__ __forceinline__ void async16(const void* g, void* l){
  __builtin_amdgcn_global_load_lds(
      (const __attribute__((address_space(1))) unsigned int*)g,
      (__attribute__((address_space(3))) unsigned int*)l, 16, 0, 0);
}

// ---------------- prep_small: weight transposes -> bf16, b1e (513-block slices) -------
__global__ __launch_bounds__(256) void prep_small(
    const float* __restrict__ w_in, const float* __restrict__ w_out,
    const float* __restrict__ ew1, const float* __restrict__ ew2,
    const float* __restrict__ nw1, const float* __restrict__ nw2,
    const float* __restrict__ eb1,
    unsigned short* __restrict__ w_in_t, unsigned short* __restrict__ w_out_t,
    unsigned short* __restrict__ ew1cat, float* __restrict__ w1r,
    float* __restrict__ b1e,
    unsigned short* __restrict__ ew2t, unsigned short* __restrict__ nw1t,
    unsigned short* __restrict__ nw2t)
{
  const int s = blockIdx.y;
  const int tid = blockIdx.x * 256 + threadIdx.x;
  if (s == 18) {
    if (tid < NL * 512) {
      int l = tid >> 9, c = tid & 511;
      b1e[tid] = (c < 256) ? eb1[l * HD + c] : 0.0f;
    }
    return;
  }
  if (s >= 2 && s < 6) {
    int l = s - 2;
    if (tid >= 513 * HD) return;
    int k = tid / HD, n = tid - k * HD;
    float v = ew1[(size_t)l * 513 * HD + tid];
    if (k == 512) { w1r[l * HD + n] = v; return; }
    unsigned short* dst = ew1cat + (size_t)l * 512 * 256;
    if (k < 256) dst[(size_t)n * 256 + k] = f2bf(v);
    else         dst[(size_t)(256 + n) * 256 + (k - 256)] = f2bf(v);
    return;
  }
  const float* src; unsigned short* dst; int K, N;
  if (s == 0)      { src = w_in;  dst = w_in_t;  K = NF;   N = HD; }
  else if (s == 1) { src = w_out; dst = w_out_t; K = HD;   N = NF; }
  else if (s < 10) { int l = s-6;  src = ew2 + (size_t)l*HD*HD;   dst = ew2t + (size_t)l*HD*HD;  K = HD;   N = HD; }
  else if (s < 14) { int l = s-10; src = nw1 + (size_t)l*2*HD*HD; dst = nw1t + (size_t)l*HD*512; K = 2*HD; N = HD; }
  else             { int l = s-14; src = nw2 + (size_t)l*HD*HD;   dst = nw2t + (size_t)l*HD*HD;  K = HD;   N = HD; }
  if (tid >= K * N) return;
  int k = tid / N, n = tid - k * N;
  dst[(size_t)n * K + k] = f2bf(src[tid]);
}

// ---------------- prep_big: h->bf16, radial ----------------
__global__ __launch_bounds__(256) void prep_big(
    const float* __restrict__ h_in, const float* __restrict__ cd,
    unsigned short* __restrict__ hb_in, float* __restrict__ radial)
{
  const int s = blockIdx.y;
  const int tid = blockIdx.x * 256 + threadIdx.x;
  if (s == 0) {
    if (tid < NN * NF) hb_in[tid] = f2bf(h_in[tid]);
  } else {
    if (tid < NE) {
      float x = cd[tid*3+0], y = cd[tid*3+1], z = cd[tid*3+2];
      radial[tid] = x*x + y*y + z*z;
    }
  }
}

// ---------------- counting sort of edges by row ----------------
__global__ __launch_bounds__(256) void hist_k(const int* __restrict__ erow, int* __restrict__ hist){
  int e = blockIdx.x * 256 + threadIdx.x;
  if (e < NE){
    unsigned r = (unsigned)erow[e]; if (r >= NN) r = 0;
    atomicAdd(&hist[r], 1);
  }
}

__global__ __launch_bounds__(256) void scan_k(const int* __restrict__ hist,
                                              int* __restrict__ starts, int* __restrict__ cursor){
  __shared__ int part[256];
  const int t = threadIdx.x;
  const int CH = 79;
  int lo = t * CH, hi = lo + CH; if (hi > NN) hi = NN; if (lo > NN) lo = NN;
  int s = 0;
  for (int i = lo; i < hi; ++i) s += hist[i];
  part[t] = s; __syncthreads();
  for (int off = 1; off < 256; off <<= 1){
    int v = (t >= off) ? part[t - off] : 0;
    __syncthreads();
    part[t] += v;
    __syncthreads();
  }
  int base = (t == 0) ? 0 : part[t - 1];
  for (int i = lo; i < hi; ++i){ starts[i] = base; cursor[i] = base; base += hist[i]; }
  if (t == 255) starts[NN] = part[255];
}

// scatter materializes (row,col) pairs and re-sorted radial at the sorted slot
__global__ __launch_bounds__(256) void scatter_k(const int* __restrict__ erow,
                                                 const int* __restrict__ ecol,
                                                 const float* __restrict__ radial,
                                                 int* __restrict__ cursor,
                                                 int* __restrict__ rowcol,
                                                 float* __restrict__ radial_s){
  int e = blockIdx.x * 256 + threadIdx.x;
  if (e < NE){
    unsigned r = (unsigned)erow[e]; if (r >= NN) r = 0;
    unsigned c = (unsigned)ecol[e]; if (c >= NN) c = 0;
    int pos = atomicAdd(&cursor[r], 1);
    rowcol[2*pos]   = (int)r;
    rowcol[2*pos+1] = (int)c;
    radial_s[pos] = radial[e];
  }
}

// ---------------- generic 128x128 bf16 MFMA GEMM: out = [silu](A @ Wt^T + bias) ------
__global__ __launch_bounds__(256) void gemm_k(
    const unsigned short* __restrict__ Am, const unsigned short* __restrict__ Wt,
    const float* __restrict__ bias,
    unsigned short* __restrict__ outB, float* __restrict__ outF,
    int M, int N, int K, int lda, int ldc, int fuseSilu)
{
  __shared__ __align__(16) unsigned short As[128*32];
  __shared__ __align__(16) unsigned short Bs[128*32];
  const int t = threadIdx.x;
  const int lane = t & 63, wave = t >> 6;
  const int ln15 = lane & 15, q = lane >> 4;
  const int bm = blockIdx.x, bn = blockIdx.y;
  const int wm = wave >> 1, wn = wave & 1;

  f32x4 acc[4][4];
  #pragma unroll
  for (int i = 0; i < 4; ++i)
    #pragma unroll
    for (int j = 0; j < 4; ++j) acc[i][j] = (f32x4){0.f,0.f,0.f,0.f};

  const int sr = t >> 2;
  const int sc = (t & 3) * 8;
  int am0 = bm*128 + sr;      if (am0 > M-1) am0 = M-1;
  int am1 = bm*128 + 64 + sr; if (am1 > M-1) am1 = M-1;
  int an0 = bn*128 + sr;      if (an0 > N-1) an0 = N-1;
  int an1 = bn*128 + 64 + sr; if (an1 > N-1) an1 = N-1;
  const unsigned short* a0 = Am + (size_t)am0 * lda + sc;
  const unsigned short* a1 = Am + (size_t)am1 * lda + sc;
  const unsigned short* b0 = Wt + (size_t)an0 * K + sc;
  const unsigned short* b1 = Wt + (size_t)an1 * K + sc;

  const int nkt = K >> 5;
  for (int kt = 0; kt < nkt; ++kt) {
    const int k0 = kt * 32;
    async16(a0 + k0, &As[t*8]);
    async16(a1 + k0, &As[2048 + t*8]);
    async16(b0 + k0, &Bs[t*8]);
    async16(b1 + k0, &Bs[2048 + t*8]);
    __syncthreads();
    short8 fa[4], fb[4];
    #pragma unroll
    for (int i = 0; i < 4; ++i)
      fa[i] = *(const short8*)&As[(wm*64 + i*16 + ln15)*32 + q*8];
    #pragma unroll
    for (int j = 0; j < 4; ++j)
      fb[j] = *(const short8*)&Bs[(wn*64 + j*16 + ln15)*32 + q*8];
    #pragma unroll
    for (int i = 0; i < 4; ++i)
      #pragma unroll
      for (int j = 0; j < 4; ++j)
        acc[i][j] = __builtin_amdgcn_mfma_f32_16x16x32_bf16(fa[i], fb[j], acc[i][j], 0, 0, 0);
    __syncthreads();
  }

  #pragma unroll
  for (int i = 0; i < 4; ++i) {
    #pragma unroll
    for (int j = 0; j < 4; ++j) {
      const int n = bn*128 + wn*64 + j*16 + ln15;
      if (n >= N) continue;
      const float bv = bias ? bias[n] : 0.0f;
      #pragma unroll
      for (int r = 0; r < 4; ++r) {
        const int m = bm*128 + wm*64 + i*16 + q*4 + r;
        if (m >= M) continue;
        float v = acc[i][j][r] + bv;
        if (fuseSilu) v = silu_f(v);
        if (outB) outB[(size_t)m * ldc + n] = f2bf(v);
        else      outF[(size_t)m * ldc + n] = v;
      }
    }
  }
}

// ---------------- fused node MLP: hcur = silu([hcur|bf16(agg)]@W1^T+b1) @ W2^T + b2 ---
// One block per 64-row strip. x1 never leaves LDS. aggF strip zeroed in passing.
// In-place safe: each block reads/writes only its own 64 rows of hcur.
__global__ __launch_bounds__(256, 3) void node_k(
    unsigned short* __restrict__ hcur,      // [NN][256] bf16, read (k<256) + write
    float* __restrict__ aggF,               // [NN][256] fp32, read (k>=256) + zero
    const unsigned short* __restrict__ w1t, // [256][512]
    const float* __restrict__ b1,
    const unsigned short* __restrict__ w2t, // [256][256]
    const float* __restrict__ b2,
    int M)
{
  __shared__ __align__(16) unsigned short As[64*32];      // 4 KB
  __shared__ __align__(16) unsigned short Bs[256*32];     // 16 KB
  __shared__ __align__(16) unsigned short x1L[8*64*32];   // 32 KB, kt-blocked
  const int t = threadIdx.x;
  const int lane = t & 63, wave = t >> 6;
  const int ln15 = lane & 15, q = lane >> 4;
  const int bm = blockIdx.x;
  const int sr = t >> 2;
  const int sc = (t & 3) * 8;

  const int row = bm*64 + sr;
  const int valid = (row < M);
  const int rowc = valid ? row : (M - 1);
  const unsigned short* aSrc = hcur + (size_t)rowc * HD + sc;
  float* gSrc = aggF + (size_t)rowc * HD + sc;

  float bv1[4], bv2[4];
  #pragma unroll
  for (int j = 0; j < 4; ++j) {
    bv1[j] = b1[wave*64 + j*16 + ln15];
    bv2[j] = b2[wave*64 + j*16 + ln15];
  }

  f32x4 acc[4][4];
  #pragma unroll
  for (int i = 0; i < 4; ++i)
    #pragma unroll
    for (int j = 0; j < 4; ++j) acc[i][j] = (f32x4){0.f,0.f,0.f,0.f};

  // ---------- phase A: K = 512 over [hcur | bf16(aggF)] ----------
  for (int kt = 0; kt < 16; ++kt) {
    if (kt < 8) {
      async16(aSrc + kt*32, &As[t*8]);
    } else {
      union { unsigned int u[4]; short8 s8; } cv;
      if (valid) {
        float* p = gSrc + (kt-8)*32;
        float4 a0 = *(const float4*)p;
        float4 a1 = *(const float4*)(p + 4);
        cv.u[0] = pk2bf(a0.x, a0.y); cv.u[1] = pk2bf(a0.z, a0.w);
        cv.u[2] = pk2bf(a1.x, a1.y); cv.u[3] = pk2bf(a1.z, a1.w);
        // zero the strip for next layer's edge_k (same-lane load->store, aggcvt pattern)
        *(float4*)p = float4{0.f,0.f,0.f,0.f};
        *(float4*)(p + 4) = float4{0.f,0.f,0.f,0.f};
      } else {
        cv.u[0] = cv.u[1] = cv.u[2] = cv.u[3] = 0u;
      }
      *(short8*)&As[t*8] = cv.s8;
    }
    // stage W1t rows 0..255, k-slice kt*32..+32
    #pragma unroll
    for (int i = 0; i < 4; ++i)
      async16(w1t + (size_t)(i*64 + sr) * 512 + kt*32 + sc, &Bs[i*2048 + t*8]);
    __syncthreads();
    short8 fa[4], fb[4];
    #pragma unroll
    for (int i = 0; i < 4; ++i) fa[i] = *(const short8*)&As[(i*16 + ln15)*32 + q*8];
    #pragma unroll
    for (int j = 0; j < 4; ++j) fb[j] = *(const short8*)&Bs[(wave*64 + j*16 + ln15)*32 + q*8];
    #pragma unroll
    for (int i = 0; i < 4; ++i)
      #pragma unroll
      for (int j = 0; j < 4; ++j)
        acc[i][j] = __builtin_amdgcn_mfma_f32_16x16x32_bf16(fa[i], fb[j], acc[i][j], 0, 0, 0);
    __syncthreads();
  }

  // x1 = silu(acc + b1) -> x1L (kt2-blocked: [kt2][row][k&31])
  #pragma unroll
  for (int i = 0; i < 4; ++i) {
    #pragma unroll
    for (int j = 0; j < 4; ++j) {
      const int k = wave*64 + j*16 + ln15;
      const int kt2 = k >> 5, k31 = k & 31;
      const f32x2 b2v = (f32x2){bv1[j], bv1[j]};
      f32x2 s01 = (f32x2){acc[i][j][0], acc[i][j][1]} + b2v;
      f32x2 s23 = (f32x2){acc[i][j][2], acc[i][j][3]} + b2v;
      f32x2 r01 = silu2(s01);
      f32x2 r23 = silu2(s23);
      const int r0 = i*16 + q*4;
      x1L[kt2*2048 + (r0  )*32 + k31] = f2bf(r01.x);
      x1L[kt2*2048 + (r0+1)*32 + k31] = f2bf(r01.y);
      x1L[kt2*2048 + (r0+2)*32 + k31] = f2bf(r23.x);
      x1L[kt2*2048 + (r0+3)*32 + k31] = f2bf(r23.y);
    }
  }
  #pragma unroll
  for (int i = 0; i < 4; ++i)
    #pragma unroll
    for (int j = 0; j < 4; ++j) acc[i][j] = (f32x4){0.f,0.f,0.f,0.f};

  // ---------- phase B: K = 256, A = x1 (LDS), B = W2t ----------
  for (int kt2 = 0; kt2 < 8; ++kt2) {
    #pragma unroll
    for (int i = 0; i < 4; ++i)
      async16(w2t + (size_t)(i*64 + sr) * 256 + kt2*32 + sc, &Bs[i*2048 + t*8]);
    __syncthreads();
    short8 fa[4], fb[4];
    #pragma unroll
    for (int i = 0; i < 4; ++i) fa[i] = *(const short8*)&x1L[kt2*2048 + (i*16 + ln15)*32 + q*8];
    #pragma unroll
    for (int j = 0; j < 4; ++j) fb[j] = *(const short8*)&Bs[(wave*64 + j*16 + ln15)*32 + q*8];
    #pragma unroll
    for (int i = 0; i < 4; ++i)
      #pragma unroll
      for (int j = 0; j < 4; ++j)
        acc[i][j] = __builtin_amdgcn_mfma_f32_16x16x32_bf16(fa[i], fb[j], acc[i][j], 0, 0, 0);
    __syncthreads();
  }

  // epilogue: hcur = acc + b2 (no silu), bf16, in-place
  #pragma unroll
  for (int i = 0; i < 4; ++i) {
    #pragma unroll
    for (int j = 0; j < 4; ++j) {
      const int n = wave*64 + j*16 + ln15;
      #pragma unroll
      for (int r = 0; r < 4; ++r) {
        const int m = bm*64 + i*16 + q*4 + r;
        if (m >= M) continue;
        hcur[(size_t)m * HD + n] = f2bf(acc[i][j][r] + bv2[j]);
      }
    }
  }
}

// ---------------- fused edge MLP + aggregation (bf16 hT, stride-640 destagger) --------
__global__ __launch_bounds__(256, 4) void edge_k(
    const unsigned short* __restrict__ hT,   // [NN][HTS] bf16, cols 0..511 valid
    const int* __restrict__ rowcol,          // [NE][2] sorted (row,col)
    const float* __restrict__ radial_s,      // [NE] sorted radial
    const float* __restrict__ w1r,           // [256]
    const unsigned short* __restrict__ w2t,  // [256][256]
    const float* __restrict__ b2,
    float* __restrict__ agg)                  // [NN][256] fp32, pre-zeroed
{
  __shared__ __align__(16) unsigned short MBUF[16896];   // 33.8 KB
  __shared__ int   rowS[64];
  __shared__ float w1rS[256];
  unsigned short* M1  = MBUF;
  unsigned short* m2T = MBUF;

  const int t = threadIdx.x;
  const int lane = t & 63, wave = t >> 6;
  const int ln15 = lane & 15, q = lane >> 4;
  // chunked XCD swizzle: XCD k owns a contiguous 1/8 of sorted-edge space (hr L2 reuse)
  int blk = blockIdx.x;
  blk = (blk & 7) * ((int)gridDim.x >> 3) + (blk >> 3);
  const int e0 = blk * 64;
  const int sr = t >> 2;
  const int sc_swz = (((t & 3) ^ ((sr >> 1) & 3))) * 8;
  const int xq = ((q ^ ((ln15 >> 1) & 3))) * 8;

  // early small loads (before the 16 gathers: vmcnt retires in issue order)
  const int2 rc = *(const int2*)(rowcol + 2*(e0 + sr));   // gather base (1 load)
  int rowv = 0;
  if (t < 64) rowv = rowcol[2*(e0 + t)];
  const float w1v = w1r[t];
  const float rad = radial_s[e0 + sr];

  float bv2[4];
  #pragma unroll
  for (int j = 0; j < 4; ++j) bv2[j] = b2[wave*64 + j*16 + ln15];

  const unsigned short* hr = hT + (size_t)rc.x * HTS + sc_swz;
  const unsigned short* hc = hT + (size_t)rc.y * HTS + 256 + sc_swz;

  // batch all 16 gather b128s into registers, interleaved
  short8 va[8], vb[8];
  #pragma unroll
  for (int ch = 0; ch < 8; ++ch) {
    va[ch] = *(const short8*)(hr + ch*32);
    vb[ch] = *(const short8*)(hc + ch*32);
  }

  if (t < 64) rowS[t] = rowv;
  w1rS[t] = w1v;

  const unsigned short* w2row[4];
  #pragma unroll
  for (int j = 0; j < 4; ++j)
    w2row[j] = w2t + (size_t)(wave*64 + j*16 + ln15) * HD + q*8;

  __syncthreads();

  // prologue: m1 = silu(hr + hc + rad*w1r) -> M1 (kt-blocked, swizzled), b128 stores
  const f32x2 rad2 = (f32x2){rad, rad};
  #pragma unroll
  for (int ch = 0; ch < 8; ++ch) {
    const int c0 = ch*32 + sc_swz;
    const unsigned int* ua = (const unsigned int*)&va[ch];
    const unsigned int* ub = (const unsigned int*)&vb[ch];
    union { unsigned int u[4]; short8 s; } res;
    #pragma unroll
    for (int i = 0; i < 4; ++i) {
      union { unsigned int i; float f; } alo, ahi, blo, bhi;
      alo.i = ua[i] << 16; ahi.i = ua[i] & 0xFFFF0000u;
      blo.i = ub[i] << 16; bhi.i = ub[i] & 0xFFFF0000u;
      f32x2 av = (f32x2){alo.f, ahi.f};
      f32x2 bv = (f32x2){blo.f, bhi.f};
      f32x2 wv = *(const f32x2*)&w1rS[c0 + 2*i];
      f32x2 o = av + bv;
      o = o + rad2 * wv;            // pk fma
      f32x2 sv = silu2(o);
      res.u[i] = pk2bf(sv.x, sv.y);
    }
    *(short8*)&M1[ch*2048 + sr*32 + (t & 3)*8] = res.s;
  }
  __syncthreads();

  // phase 2: K = 256 (M1 @ W2^T); fb direct from global (L2-resident w2t)
  f32x4 acc2[4][4];
  #pragma unroll
  for (int i = 0; i < 4; ++i)
    #pragma unroll
    for (int j = 0; j < 4; ++j) acc2[i][j] = (f32x4){0.f,0.f,0.f,0.f};

  __builtin_amdgcn_s_setprio(1);
  #pragma unroll
  for (int kt = 0; kt < 8; ++kt) {
    short8 fa[4], fb[4];
    #pragma unroll
    for (int j = 0; j < 4; ++j) fb[j] = *(const short8*)(w2row[j] + kt*32);
    #pragma unroll
    for (int i = 0; i < 4; ++i) fa[i] = *(const short8*)&M1[kt*2048 + (i*16 + ln15)*32 + xq];
    #pragma unroll
    for (int i = 0; i < 4; ++i)
      #pragma unroll
      for (int j = 0; j < 4; ++j)
        acc2[i][j] = __builtin_amdgcn_mfma_f32_16x16x32_bf16(fa[i], fb[j], acc2[i][j], 0, 0, 0);
  }
  __builtin_amdgcn_s_setprio(0);
  __syncthreads();

  // epilogue 2a: silu -> m2T[col][stride 66] in LDS (pk math)
  #pragma unroll
  for (int i = 0; i < 4; ++i) {
    #pragma unroll
    for (int j = 0; j < 4; ++j) {
      const int n = wave*64 + j*16 + ln15;
      const f32x2 b2v = (f32x2){bv2[j], bv2[j]};
      f32x2 s01 = (f32x2){acc2[i][j][0], acc2[i][j][1]} + b2v;
      f32x2 s23 = (f32x2){acc2[i][j][2], acc2[i][j][3]} + b2v;
      f32x2 r01 = silu2(s01);
      f32x2 r23 = silu2(s23);
      const int m = i*16 + q*4;
      *(unsigned int*)&m2T[n*66 + m]     = pk2bf(r01.x, r01.y);
      *(unsigned int*)&m2T[n*66 + m + 2] = pk2bf(r23.x, r23.y);
    }
  }
  __syncthreads();

  // epilogue 2b: per-column segmented reduction (rowS readfirstlane -> scalar cmps)
  {
    const int c = t;
    int cur = __builtin_amdgcn_readfirstlane(rowS[0]);
    float s = 0.f;
    #pragma unroll
    for (int m = 0; m < 64; m += 4) {
      unsigned int u0 = *(const unsigned int*)&m2T[c*66 + m];
      unsigned int u1 = *(const unsigned int*)&m2T[c*66 + m + 2];
      int n0 = __builtin_amdgcn_readfirstlane(rowS[m]);
      int n1 = __builtin_amdgcn_readfirstlane(rowS[m+1]);
      int n2 = __builtin_amdgcn_readfirstlane(rowS[m+2]);
      int n3 = __builtin_amdgcn_readfirstlane(rowS[m+3]);
      float f0 = bf2f((unsigned short)u0), f1 = bf2f((unsigned short)(u0 >> 16));
      float f2v = bf2f((unsigned short)u1), f3 = bf2f((unsigned short)(u1 >> 16));
      if (n0 != cur) { atomicAdd(&agg[(size_t)cur * HD + c], s); s = 0.f; cur = n0; }
      s += f0;
      if (n1 != cur) { atomicAdd(&agg[(size_t)cur * HD + c], s); s = 0.f; cur = n1; }
      s += f1;
      if (n2 != cur) { atomicAdd(&agg[(size_t)cur * HD + c], s); s = 0.f; cur = n2; }
      s += f2v;
      if (n3 != cur) { atomicAdd(&agg[(size_t)cur * HD + c], s); s = 0.f; cur = n3; }
      s += f3;
    }
    atomicAdd(&agg[(size_t)cur * HD + c], s);
  }
}

// ---------------- launch ----------------
extern "C" void kernel_launch(void* const* d_in, const int* in_sizes, int n_in,
                              void* d_out, int out_size, void* d_ws, size_t ws_size,
                              hipStream_t stream)
{
  (void)in_sizes; (void)n_in; (void)out_size; (void)ws_size;
  const float* h_in  = (const float*)d_in[0];
  const int*   ei    = (const int*)d_in[1];
  const float* cd    = (const float*)d_in[2];
  const float* w_in  = (const float*)d_in[3];
  const float* b_in  = (const float*)d_in[4];
  const float* w_out = (const float*)d_in[5];
  const float* b_out = (const float*)d_in[6];
  const float* ew1   = (const float*)d_in[7];
  const float* eb1   = (const float*)d_in[8];
  const float* ew2   = (const float*)d_in[9];
  const float* eb2   = (const float*)d_in[10];
  const float* nw1   = (const float*)d_in[11];
  const float* nb1   = (const float*)d_in[12];
  const float* nw2   = (const float*)d_in[13];
  const float* nb2   = (const float*)d_in[14];
  float* out = (float*)d_out;

  char* base = (char*)d_ws;
  size_t off = 0;
  auto WS = [&](size_t bytes) -> char* {
    char* p = base + off;
    off = (off + bytes + 255) & ~(size_t)255;
    return p;
  };
  float*          radial  = (float*)WS((size_t)NE * 4);
  unsigned short* hb_in   = (unsigned short*)WS((size_t)NN * NF * 2);
  unsigned short* hcur    = (unsigned short*)WS((size_t)NN * HD * 2);
  float*          aggF    = (float*)WS((size_t)NN * HD * 4);
  unsigned short* hT      = (unsigned short*)WS((size_t)NN * HTS * 2);  // 25.6 MB bf16
  unsigned short* w_in_t  = (unsigned short*)WS((size_t)NF * HD * 2);
  unsigned short* w_out_t = (unsigned short*)WS((size_t)NF * HD * 2);
  unsigned short* ew1cat  = (unsigned short*)WS((size_t)NL * 512 * 256 * 2);
  float*          w1r     = (float*)WS((size_t)NL * HD * 4);
  float*          b1e     = (float*)WS((size_t)NL * 512 * 4);
  unsigned short* ew2t    = (unsigned short*)WS((size_t)NL * HD * HD * 2);
  unsigned short* nw1t    = (unsigned short*)WS((size_t)NL * HD * 512 * 2);
  unsigned short* nw2t    = (unsigned short*)WS((size_t)NL * HD * HD * 2);
  int*            hist    = (int*)WS((size_t)NN * 4);
  int*            starts  = (int*)WS((size_t)(NN + 1) * 4);
  int*            cursor  = (int*)WS((size_t)NN * 4);
  int*            rowcol  = (int*)WS((size_t)NE * 2 * 4);
  float*          radial_s= (float*)WS((size_t)NE * 4);

  hipMemsetAsync(hist, 0, (size_t)NN * 4, stream);
  hipMemsetAsync(aggF, 0, (size_t)NN * HD * 4, stream);
  prep_small<<<dim3(513, 19), 256, 0, stream>>>(w_in, w_out, ew1, ew2, nw1, nw2, eb1,
      w_in_t, w_out_t, ew1cat, w1r, b1e, ew2t, nw1t, nw2t);
  prep_big<<<dim3(5000, 2), 256, 0, stream>>>(h_in, cd, hb_in, radial);
  hist_k<<<NE / 256, 256, 0, stream>>>(ei, hist);
  scan_k<<<1, 256, 0, stream>>>(hist, starts, cursor);
  scatter_k<<<NE / 256, 256, 0, stream>>>(ei, ei + NE, radial, cursor, rowcol, radial_s);

  // h = h_in @ w_in + b_in
  gemm_k<<<dim3(157, 2), 256, 0, stream>>>(hb_in, w_in_t, b_in, hcur, nullptr,
      NN, HD, NF, NF, HD, 0);

  for (int l = 0; l < NL; ++l) {
    // node-level phase-1 table (bf16, destaggered stride): hT = hcur @ W1cat^T + b1e
    gemm_k<<<dim3(157, 4), 256, 0, stream>>>(hcur, ew1cat + (size_t)l * 512 * 256,
        b1e + (size_t)l * 512, hT, nullptr, NN, 512, HD, HD, HTS, 0);
    edge_k<<<NE / 64, 256, 0, stream>>>(hT, rowcol, radial_s,
        w1r + l * HD, ew2t + (size_t)l * HD * HD, eb2 + l * HD, aggF);
    // fused node MLP (replaces nw1-gemm + nw2-gemm + aggcvt); zeroes aggF strip
    node_k<<<(NN + 63) / 64, 256, 0, stream>>>(hcur, aggF,
        nw1t + (size_t)l * HD * 512, nb1 + l * HD,
        nw2t + (size_t)l * HD * HD, nb2 + l * HD, NN);
  }

  // out = h @ w_out + b_out  (fp32 output)
  gemm_k<<<dim3(157, 1), 256, 0, stream>>>(hcur, w_out_t, b_out, nullptr, out,
      NN, NF, HD, HD, NF, 0);
}

// Round 6
// 1224.462 us; speedup vs baseline: 1.5826x; 1.0065x over previous
//
#include <hip/hip_runtime.h>
#include <hip/hip_bf16.h>
#include <cstdint>
#include <cstddef>

#define NN 20000
#define NE 640000
#define NF 64
#define HD 256
#define NL 4
#define HTS 640   // hT row stride in shorts: 1280 B = 5x256 B (destaggers HBM channels)

typedef __attribute__((ext_vector_type(8))) short short8;
typedef __attribute__((ext_vector_type(4))) float f32x4;
typedef __attribute__((ext_vector_type(2))) float f32x2;

__device__ __forceinline__ float bf2f(unsigned short u){
  union { unsigned int i; float f; } x; x.i = ((unsigned int)u) << 16; return x.f;
}
__device__ __forceinline__ unsigned short f2bf(float f){
  union { float f; unsigned int i; } x; x.f = f;
  unsigned int r = x.i + 0x7FFFu + ((x.i >> 16) & 1u);   // RNE
  return (unsigned short)(r >> 16);
}
// packed 2xf32 -> 2xbf16 (v_cvt_pk_bf16_f32 on gfx950, RNE)
__device__ __forceinline__ unsigned int pk2bf(float a, float b){
  union { __hip_bfloat162 h; unsigned int u; } cv;
  cv.h = __float22bfloat162_rn(float2{a, b});
  return cv.u;
}
// silu via guaranteed-native v_exp_f32 + v_rcp_f32
__device__ __forceinline__ float silu_f(float v){
  float e = __builtin_amdgcn_exp2f(v * -1.442695041f);
  return v * __builtin_amdgcn_rcpf(1.0f + e);
}
// packed silu on 2 lanes: pk mul/add around the 2 scalar trans ops
__device__ __forceinline__ f32x2 silu2(f32x2 v){
  f32x2 t = v * (f32x2){-1.442695041f, -1.442695041f};   // v_pk_mul_f32
  f32x2 e = (f32x2){__builtin_amdgcn_exp2f(t.x), __builtin_amdgcn_exp2f(t.y)};
  f32x2 d = e + (f32x2){1.0f, 1.0f};                      // v_pk_add_f32
  f32x2 r = (f32x2){__builtin_amdgcn_rcpf(d.x), __builtin_amdgcn_rcpf(d.y)};
  return v * r;                                           // v_pk_mul_f32
}
__device__ __forceinline__ void async16(const void* g, void* l){
  __builtin_amdgcn_global_load_lds(
      (const __attribute__((address_space(1))) unsigned int*)g,
      (__attribute__((address_space(3))) unsigned int*)l, 16, 0, 0);
}

// ---------------- prep_small: weight transposes -> bf16, b1e (513-block slices) -------
__global__ __launch_bounds__(256) void prep_small(
    const float* __restrict__ w_in, const float* __restrict__ w_out,
    const float* __restrict__ ew1, const float* __restrict__ ew2,
    const float* __restrict__ nw1, const float* __restrict__ nw2,
    const float* __restrict__ eb1,
    unsigned short* __restrict__ w_in_t, unsigned short* __restrict__ w_out_t,
    unsigned short* __restrict__ ew1cat, float* __restrict__ w1r,
    float* __restrict__ b1e,
    unsigned short* __restrict__ ew2t, unsigned short* __restrict__ nw1t,
    unsigned short* __restrict__ nw2t)
{
  const int s = blockIdx.y;
  const int tid = blockIdx.x * 256 + threadIdx.x;
  if (s == 18) {
    if (tid < NL * 512) {
      int l = tid >> 9, c = tid & 511;
      b1e[tid] = (c < 256) ? eb1[l * HD + c] : 0.0f;
    }
    return;
  }
  if (s >= 2 && s < 6) {
    int l = s - 2;
    if (tid >= 513 * HD) return;
    int k = tid / HD, n = tid - k * HD;
    float v = ew1[(size_t)l * 513 * HD + tid];
    if (k == 512) { w1r[l * HD + n] = v; return; }
    unsigned short* dst = ew1cat + (size_t)l * 512 * 256;
    if (k < 256) dst[(size_t)n * 256 + k] = f2bf(v);
    else         dst[(size_t)(256 + n) * 256 + (k - 256)] = f2bf(v);
    return;
  }
  const float* src; unsigned short* dst; int K, N;
  if (s == 0)      { src = w_in;  dst = w_in_t;  K = NF;   N = HD; }
  else if (s == 1) { src = w_out; dst = w_out_t; K = HD;   N = NF; }
  else if (s < 10) { int l = s-6;  src = ew2 + (size_t)l*HD*HD;   dst = ew2t + (size_t)l*HD*HD;  K = HD;   N = HD; }
  else if (s < 14) { int l = s-10; src = nw1 + (size_t)l*2*HD*HD; dst = nw1t + (size_t)l*HD*512; K = 2*HD; N = HD; }
  else             { int l = s-14; src = nw2 + (size_t)l*HD*HD;   dst = nw2t + (size_t)l*HD*HD;  K = HD;   N = HD; }
  if (tid >= K * N) return;
  int k = tid / N, n = tid - k * N;
  dst[(size_t)n * K + k] = f2bf(src[tid]);
}

// ---------------- prep_big: h->bf16, radial ----------------
__global__ __launch_bounds__(256) void prep_big(
    const float* __restrict__ h_in, const float* __restrict__ cd,
    unsigned short* __restrict__ hb_in, float* __restrict__ radial)
{
  const int s = blockIdx.y;
  const int tid = blockIdx.x * 256 + threadIdx.x;
  if (s == 0) {
    if (tid < NN * NF) hb_in[tid] = f2bf(h_in[tid]);
  } else {
    if (tid < NE) {
      float x = cd[tid*3+0], y = cd[tid*3+1], z = cd[tid*3+2];
      radial[tid] = x*x + y*y + z*z;
    }
  }
}

// ---------------- counting sort of edges by row ----------------
__global__ __launch_bounds__(256) void hist_k(const int* __restrict__ erow, int* __restrict__ hist){
  int e = blockIdx.x * 256 + threadIdx.x;
  if (e < NE){
    unsigned r = (unsigned)erow[e]; if (r >= NN) r = 0;
    atomicAdd(&hist[r], 1);
  }
}

__global__ __launch_bounds__(256) void scan_k(const int* __restrict__ hist,
                                              int* __restrict__ starts, int* __restrict__ cursor){
  __shared__ int part[256];
  const int t = threadIdx.x;
  const int CH = 79;
  int lo = t * CH, hi = lo + CH; if (hi > NN) hi = NN; if (lo > NN) lo = NN;
  int s = 0;
  for (int i = lo; i < hi; ++i) s += hist[i];
  part[t] = s; __syncthreads();
  for (int off = 1; off < 256; off <<= 1){
    int v = (t >= off) ? part[t - off] : 0;
    __syncthreads();
    part[t] += v;
    __syncthreads();
  }
  int base = (t == 0) ? 0 : part[t - 1];
  for (int i = lo; i < hi; ++i){ starts[i] = base; cursor[i] = base; base += hist[i]; }
  if (t == 255) starts[NN] = part[255];
}

// scatter materializes (row,col) pairs and re-sorted radial at the sorted slot
__global__ __launch_bounds__(256) void scatter_k(const int* __restrict__ erow,
                                                 const int* __restrict__ ecol,
                                                 const float* __restrict__ radial,
                                                 int* __restrict__ cursor,
                                                 int* __restrict__ rowcol,
                                                 float* __restrict__ radial_s){
  int e = blockIdx.x * 256 + threadIdx.x;
  if (e < NE){
    unsigned r = (unsigned)erow[e]; if (r >= NN) r = 0;
    unsigned c = (unsigned)ecol[e]; if (c >= NN) c = 0;
    int pos = atomicAdd(&cursor[r], 1);
    rowcol[2*pos]   = (int)r;
    rowcol[2*pos+1] = (int)c;
    radial_s[pos] = radial[e];
  }
}

// ---------------- generic 128x128 bf16 MFMA GEMM: out = [silu](A @ Wt^T + bias) ------
__global__ __launch_bounds__(256) void gemm_k(
    const unsigned short* __restrict__ Am, const unsigned short* __restrict__ Wt,
    const float* __restrict__ bias,
    unsigned short* __restrict__ outB, float* __restrict__ outF,
    int M, int N, int K, int lda, int ldc, int fuseSilu)
{
  __shared__ __align__(16) unsigned short As[128*32];
  __shared__ __align__(16) unsigned short Bs[128*32];
  const int t = threadIdx.x;
  const int lane = t & 63, wave = t >> 6;
  const int ln15 = lane & 15, q = lane >> 4;
  const int bm = blockIdx.x, bn = blockIdx.y;
  const int wm = wave >> 1, wn = wave & 1;

  f32x4 acc[4][4];
  #pragma unroll
  for (int i = 0; i < 4; ++i)
    #pragma unroll
    for (int j = 0; j < 4; ++j) acc[i][j] = (f32x4){0.f,0.f,0.f,0.f};

  const int sr = t >> 2;
  const int sc = (t & 3) * 8;
  int am0 = bm*128 + sr;      if (am0 > M-1) am0 = M-1;
  int am1 = bm*128 + 64 + sr; if (am1 > M-1) am1 = M-1;
  int an0 = bn*128 + sr;      if (an0 > N-1) an0 = N-1;
  int an1 = bn*128 + 64 + sr; if (an1 > N-1) an1 = N-1;
  const unsigned short* a0 = Am + (size_t)am0 * lda + sc;
  const unsigned short* a1 = Am + (size_t)am1 * lda + sc;
  const unsigned short* b0 = Wt + (size_t)an0 * K + sc;
  const unsigned short* b1 = Wt + (size_t)an1 * K + sc;

  const int nkt = K >> 5;
  for (int kt = 0; kt < nkt; ++kt) {
    const int k0 = kt * 32;
    async16(a0 + k0, &As[t*8]);
    async16(a1 + k0, &As[2048 + t*8]);
    async16(b0 + k0, &Bs[t*8]);
    async16(b1 + k0, &Bs[2048 + t*8]);
    __syncthreads();
    short8 fa[4], fb[4];
    #pragma unroll
    for (int i = 0; i < 4; ++i)
      fa[i] = *(const short8*)&As[(wm*64 + i*16 + ln15)*32 + q*8];
    #pragma unroll
    for (int j = 0; j < 4; ++j)
      fb[j] = *(const short8*)&Bs[(wn*64 + j*16 + ln15)*32 + q*8];
    #pragma unroll
    for (int i = 0; i < 4; ++i)
      #pragma unroll
      for (int j = 0; j < 4; ++j)
        acc[i][j] = __builtin_amdgcn_mfma_f32_16x16x32_bf16(fa[i], fb[j], acc[i][j], 0, 0, 0);
    __syncthreads();
  }

  #pragma unroll
  for (int i = 0; i < 4; ++i) {
    #pragma unroll
    for (int j = 0; j < 4; ++j) {
      const int n = bn*128 + wn*64 + j*16 + ln15;
      if (n >= N) continue;
      const float bv = bias ? bias[n] : 0.0f;
      #pragma unroll
      for (int r = 0; r < 4; ++r) {
        const int m = bm*128 + wm*64 + i*16 + q*4 + r;
        if (m >= M) continue;
        float v = acc[i][j][r] + bv;
        if (fuseSilu) v = silu_f(v);
        if (outB) outB[(size_t)m * ldc + n] = f2bf(v);
        else      outF[(size_t)m * ldc + n] = v;
      }
    }
  }
}

// ---------------- fused node MLP + next-layer hT ----------------
// 32-row strips (625 blocks: 2.44/CU load balance).
// A: x1 = silu([hcur|bf16(agg)] @ W1^T + b1)   (x1 in LDS only; agg strip zeroed)
// B: hcur = x1 @ W2^T + b2                     (in-place; strip also kept in LDS)
// C: hT = hcur_strip @ ew1cat_next^T + b1e_next (replaces per-layer hT GEMM)
__global__ __launch_bounds__(256, 4) void node_k(
    unsigned short* __restrict__ hcur,      // [NN][256] bf16, read (k<256) + write
    float* __restrict__ aggF,               // [NN][256] fp32, read (k>=256) + zero
    const unsigned short* __restrict__ w1t, // [256][512]
    const float* __restrict__ b1,
    const unsigned short* __restrict__ w2t, // [256][256]
    const float* __restrict__ b2,
    const unsigned short* __restrict__ w1cat_next, // [512][256] or null
    const float* __restrict__ b1e_next,            // [512] or null
    unsigned short* __restrict__ hT,               // [NN][HTS] out (if w1cat_next)
    int M)
{
  __shared__ __align__(16) unsigned short As[32*32];      // 2 KB
  __shared__ __align__(16) unsigned short Bs[256*32];     // 16 KB
  __shared__ __align__(16) unsigned short xL[8*32*32];    // 16 KB (x1, then hcur strip)
  const int t = threadIdx.x;
  const int lane = t & 63, wave = t >> 6;
  const int ln15 = lane & 15, q = lane >> 4;
  const int bm = blockIdx.x;
  const int sc = (t & 3) * 8;
  const int srA = (t & 127) >> 2;      // 0..31 (A staging, threads 0..127)
  const int srB = t >> 2;              // 0..63 (B staging rows)

  const int rowA = bm*32 + srA;
  const unsigned short* aSrc = hcur + (size_t)rowA * HD + sc;
  float* gSrc = aggF + (size_t)rowA * HD + sc;

  float bv1[4], bv2[4];
  #pragma unroll
  for (int j = 0; j < 4; ++j) {
    bv1[j] = b1[wave*64 + j*16 + ln15];
    bv2[j] = b2[wave*64 + j*16 + ln15];
  }

  f32x4 acc[2][4];
  #pragma unroll
  for (int i = 0; i < 2; ++i)
    #pragma unroll
    for (int j = 0; j < 4; ++j) acc[i][j] = (f32x4){0.f,0.f,0.f,0.f};

  // ---------- phase A: K = 512 over [hcur | bf16(aggF)] ----------
  for (int kt = 0; kt < 16; ++kt) {
    if (t < 128) {
      if (kt < 8) {
        async16(aSrc + kt*32, &As[t*8]);
      } else {
        float* p = gSrc + (kt-8)*32;
        float4 a0 = *(const float4*)p;
        float4 a1 = *(const float4*)(p + 4);
        union { unsigned int u[4]; short8 s8; } cv;
        cv.u[0] = pk2bf(a0.x, a0.y); cv.u[1] = pk2bf(a0.z, a0.w);
        cv.u[2] = pk2bf(a1.x, a1.y); cv.u[3] = pk2bf(a1.z, a1.w);
        // zero the strip for next layer's edge_k
        *(float4*)p = float4{0.f,0.f,0.f,0.f};
        *(float4*)(p + 4) = float4{0.f,0.f,0.f,0.f};
        *(short8*)&As[t*8] = cv.s8;
      }
    }
    #pragma unroll
    for (int i = 0; i < 4; ++i)
      async16(w1t + (size_t)(i*64 + srB) * 512 + kt*32 + sc, &Bs[i*2048 + t*8]);
    __syncthreads();
    short8 fa[2], fb[4];
    #pragma unroll
    for (int i = 0; i < 2; ++i) fa[i] = *(const short8*)&As[(i*16 + ln15)*32 + q*8];
    #pragma unroll
    for (int j = 0; j < 4; ++j) fb[j] = *(const short8*)&Bs[(wave*64 + j*16 + ln15)*32 + q*8];
    #pragma unroll
    for (int i = 0; i < 2; ++i)
      #pragma unroll
      for (int j = 0; j < 4; ++j)
        acc[i][j] = __builtin_amdgcn_mfma_f32_16x16x32_bf16(fa[i], fb[j], acc[i][j], 0, 0, 0);
    __syncthreads();
  }

  // x1 = silu(acc + b1) -> xL (kt2-blocked: [kt2][row][k&31])
  #pragma unroll
  for (int i = 0; i < 2; ++i) {
    #pragma unroll
    for (int j = 0; j < 4; ++j) {
      const int k = wave*64 + j*16 + ln15;
      const int kt2 = k >> 5, k31 = k & 31;
      const f32x2 bb = (f32x2){bv1[j], bv1[j]};
      f32x2 s01 = (f32x2){acc[i][j][0], acc[i][j][1]} + bb;
      f32x2 s23 = (f32x2){acc[i][j][2], acc[i][j][3]} + bb;
      f32x2 r01 = silu2(s01);
      f32x2 r23 = silu2(s23);
      const int r0 = i*16 + q*4;
      xL[kt2*1024 + (r0  )*32 + k31] = f2bf(r01.x);
      xL[kt2*1024 + (r0+1)*32 + k31] = f2bf(r01.y);
      xL[kt2*1024 + (r0+2)*32 + k31] = f2bf(r23.x);
      xL[kt2*1024 + (r0+3)*32 + k31] = f2bf(r23.y);
    }
  }
  #pragma unroll
  for (int i = 0; i < 2; ++i)
    #pragma unroll
    for (int j = 0; j < 4; ++j) acc[i][j] = (f32x4){0.f,0.f,0.f,0.f};

  // ---------- phase B: K = 256, A = x1 (LDS), B = W2t ----------
  for (int kt2 = 0; kt2 < 8; ++kt2) {
    #pragma unroll
    for (int i = 0; i < 4; ++i)
      async16(w2t + (size_t)(i*64 + srB) * 256 + kt2*32 + sc, &Bs[i*2048 + t*8]);
    __syncthreads();
    short8 fa[2], fb[4];
    #pragma unroll
    for (int i = 0; i < 2; ++i) fa[i] = *(const short8*)&xL[kt2*1024 + (i*16 + ln15)*32 + q*8];
    #pragma unroll
    for (int j = 0; j < 4; ++j) fb[j] = *(const short8*)&Bs[(wave*64 + j*16 + ln15)*32 + q*8];
    #pragma unroll
    for (int i = 0; i < 2; ++i)
      #pragma unroll
      for (int j = 0; j < 4; ++j)
        acc[i][j] = __builtin_amdgcn_mfma_f32_16x16x32_bf16(fa[i], fb[j], acc[i][j], 0, 0, 0);
    __syncthreads();
  }

  // epilogue B: hcur = acc + b2 (no silu) -> global, AND strip -> xL for phase C
  // (all xL reads of phase B are behind the loop's final barrier)
  #pragma unroll
  for (int i = 0; i < 2; ++i) {
    #pragma unroll
    for (int j = 0; j < 4; ++j) {
      const int n = wave*64 + j*16 + ln15;
      const int kt2 = n >> 5, k31 = n & 31;
      float v0 = acc[i][j][0] + bv2[j];
      float v1 = acc[i][j][1] + bv2[j];
      float v2 = acc[i][j][2] + bv2[j];
      float v3 = acc[i][j][3] + bv2[j];
      unsigned short h0 = f2bf(v0), h1 = f2bf(v1), h2 = f2bf(v2), h3 = f2bf(v3);
      const int r0 = i*16 + q*4;
      const int m0 = bm*32 + r0;
      hcur[(size_t)(m0  ) * HD + n] = h0;
      hcur[(size_t)(m0+1) * HD + n] = h1;
      hcur[(size_t)(m0+2) * HD + n] = h2;
      hcur[(size_t)(m0+3) * HD + n] = h3;
      if (w1cat_next) {
        xL[kt2*1024 + (r0  )*32 + k31] = h0;
        xL[kt2*1024 + (r0+1)*32 + k31] = h1;
        xL[kt2*1024 + (r0+2)*32 + k31] = h2;
        xL[kt2*1024 + (r0+3)*32 + k31] = h3;
      }
    }
  }

  if (!w1cat_next) return;

  // ---------- phase C: hT strip = hcur_strip @ ew1cat_next^T + b1e_next ----------
  #pragma unroll
  for (int half = 0; half < 2; ++half) {
    #pragma unroll
    for (int i = 0; i < 2; ++i)
      #pragma unroll
      for (int j = 0; j < 4; ++j) acc[i][j] = (f32x4){0.f,0.f,0.f,0.f};
    for (int kt2 = 0; kt2 < 8; ++kt2) {
      #pragma unroll
      for (int i = 0; i < 4; ++i)
        async16(w1cat_next + (size_t)(half*256 + i*64 + srB) * 256 + kt2*32 + sc,
                &Bs[i*2048 + t*8]);
      __syncthreads();
      short8 fa[2], fb[4];
      #pragma unroll
      for (int i = 0; i < 2; ++i) fa[i] = *(const short8*)&xL[kt2*1024 + (i*16 + ln15)*32 + q*8];
      #pragma unroll
      for (int j = 0; j < 4; ++j) fb[j] = *(const short8*)&Bs[(wave*64 + j*16 + ln15)*32 + q*8];
      #pragma unroll
      for (int i = 0; i < 2; ++i)
        #pragma unroll
        for (int j = 0; j < 4; ++j)
          acc[i][j] = __builtin_amdgcn_mfma_f32_16x16x32_bf16(fa[i], fb[j], acc[i][j], 0, 0, 0);
      __syncthreads();
    }
    #pragma unroll
    for (int i = 0; i < 2; ++i) {
      #pragma unroll
      for (int j = 0; j < 4; ++j) {
        const int n = half*256 + wave*64 + j*16 + ln15;
        const float bv = b1e_next[n];
        #pragma unroll
        for (int r = 0; r < 4; ++r) {
          const int m = bm*32 + i*16 + q*4 + r;
          hT[(size_t)m * HTS + n] = f2bf(acc[i][j][r] + bv);
        }
      }
    }
  }
}

// ---------------- fused edge MLP + aggregation (bf16 hT, stride-640 destagger) --------
// (256,3): 3 blocks/CU but ~170 VGPR budget -> compiler can pipeline the 16 gathers
// and prefetch fb W2 loads across kt steps (at 64 VGPR it could not).
__global__ __launch_bounds__(256, 3) void edge_k(
    const unsigned short* __restrict__ hT,   // [NN][HTS] bf16, cols 0..511 valid
    const int* __restrict__ rowcol,          // [NE][2] sorted (row,col)
    const float* __restrict__ radial_s,      // [NE] sorted radial
    const float* __restrict__ w1r,           // [256]
    const unsigned short* __restrict__ w2t,  // [256][256]
    const float* __restrict__ b2,
    float* __restrict__ agg)                  // [NN][256] fp32, pre-zeroed
{
  __shared__ __align__(16) unsigned short MBUF[16896];   // 33.8 KB
  __shared__ int   rowS[64];
  __shared__ float w1rS[256];
  unsigned short* M1  = MBUF;
  unsigned short* m2T = MBUF;

  const int t = threadIdx.x;
  const int lane = t & 63, wave = t >> 6;
  const int ln15 = lane & 15, q = lane >> 4;
  // chunked XCD swizzle: XCD k owns a contiguous 1/8 of sorted-edge space (hr L2 reuse)
  int blk = blockIdx.x;
  blk = (blk & 7) * ((int)gridDim.x >> 3) + (blk >> 3);
  const int e0 = blk * 64;
  const int sr = t >> 2;
  const int sc_swz = (((t & 3) ^ ((sr >> 1) & 3))) * 8;
  const int xq = ((q ^ ((ln15 >> 1) & 3))) * 8;

  // early small loads (before the 16 gathers: vmcnt retires in issue order)
  const int2 rc = *(const int2*)(rowcol + 2*(e0 + sr));   // gather base (1 load)
  int rowv = 0;
  if (t < 64) rowv = rowcol[2*(e0 + t)];
  const float w1v = w1r[t];
  const float rad = radial_s[e0 + sr];

  float bv2[4];
  #pragma unroll
  for (int j = 0; j < 4; ++j) bv2[j] = b2[wave*64 + j*16 + ln15];

  const unsigned short* hr = hT + (size_t)rc.x * HTS + sc_swz;
  const unsigned short* hc = hT + (size_t)rc.y * HTS + 256 + sc_swz;

  // batch all 16 gather b128s into registers, interleaved
  short8 va[8], vb[8];
  #pragma unroll
  for (int ch = 0; ch < 8; ++ch) {
    va[ch] = *(const short8*)(hr + ch*32);
    vb[ch] = *(const short8*)(hc + ch*32);
  }

  if (t < 64) rowS[t] = rowv;
  w1rS[t] = w1v;

  const unsigned short* w2row[4];
  #pragma unroll
  for (int j = 0; j < 4; ++j)
    w2row[j] = w2t + (size_t)(wave*64 + j*16 + ln15) * HD + q*8;

  __syncthreads();

  // prologue: m1 = silu(hr + hc + rad*w1r) -> M1 (kt-blocked, swizzled), b128 stores
  const f32x2 rad2 = (f32x2){rad, rad};
  #pragma unroll
  for (int ch = 0; ch < 8; ++ch) {
    const int c0 = ch*32 + sc_swz;
    const unsigned int* ua = (const unsigned int*)&va[ch];
    const unsigned int* ub = (const unsigned int*)&vb[ch];
    union { unsigned int u[4]; short8 s; } res;
    #pragma unroll
    for (int i = 0; i < 4; ++i) {
      union { unsigned int i; float f; } alo, ahi, blo, bhi;
      alo.i = ua[i] << 16; ahi.i = ua[i] & 0xFFFF0000u;
      blo.i = ub[i] << 16; bhi.i = ub[i] & 0xFFFF0000u;
      f32x2 av = (f32x2){alo.f, ahi.f};
      f32x2 bv = (f32x2){blo.f, bhi.f};
      f32x2 wv = *(const f32x2*)&w1rS[c0 + 2*i];
      f32x2 o = av + bv;
      o = o + rad2 * wv;            // pk fma
      f32x2 sv = silu2(o);
      res.u[i] = pk2bf(sv.x, sv.y);
    }
    *(short8*)&M1[ch*2048 + sr*32 + (t & 3)*8] = res.s;
  }
  __syncthreads();

  // phase 2: K = 256 (M1 @ W2^T); fb direct from global (L2-resident w2t)
  f32x4 acc2[4][4];
  #pragma unroll
  for (int i = 0; i < 4; ++i)
    #pragma unroll
    for (int j = 0; j < 4; ++j) acc2[i][j] = (f32x4){0.f,0.f,0.f,0.f};

  __builtin_amdgcn_s_setprio(1);
  #pragma unroll
  for (int kt = 0; kt < 8; ++kt) {
    short8 fa[4], fb[4];
    #pragma unroll
    for (int j = 0; j < 4; ++j) fb[j] = *(const short8*)(w2row[j] + kt*32);
    #pragma unroll
    for (int i = 0; i < 4; ++i) fa[i] = *(const short8*)&M1[kt*2048 + (i*16 + ln15)*32 + xq];
    #pragma unroll
    for (int i = 0; i < 4; ++i)
      #pragma unroll
      for (int j = 0; j < 4; ++j)
        acc2[i][j] = __builtin_amdgcn_mfma_f32_16x16x32_bf16(fa[i], fb[j], acc2[i][j], 0, 0, 0);
  }
  __builtin_amdgcn_s_setprio(0);
  __syncthreads();

  // epilogue 2a: silu -> m2T[col][stride 66] in LDS (pk math)
  #pragma unroll
  for (int i = 0; i < 4; ++i) {
    #pragma unroll
    for (int j = 0; j < 4; ++j) {
      const int n = wave*64 + j*16 + ln15;
      const f32x2 b2v = (f32x2){bv2[j], bv2[j]};
      f32x2 s01 = (f32x2){acc2[i][j][0], acc2[i][j][1]} + b2v;
      f32x2 s23 = (f32x2){acc2[i][j][2], acc2[i][j][3]} + b2v;
      f32x2 r01 = silu2(s01);
      f32x2 r23 = silu2(s23);
      const int m = i*16 + q*4;
      *(unsigned int*)&m2T[n*66 + m]     = pk2bf(r01.x, r01.y);
      *(unsigned int*)&m2T[n*66 + m + 2] = pk2bf(r23.x, r23.y);
    }
  }
  __syncthreads();

  // epilogue 2b: per-column segmented reduction (rowS readfirstlane -> scalar cmps)
  {
    const int c = t;
    int cur = __builtin_amdgcn_readfirstlane(rowS[0]);
    float s = 0.f;
    #pragma unroll
    for (int m = 0; m < 64; m += 4) {
      unsigned int u0 = *(const unsigned int*)&m2T[c*66 + m];
      unsigned int u1 = *(const unsigned int*)&m2T[c*66 + m + 2];
      int n0 = __builtin_amdgcn_readfirstlane(rowS[m]);
      int n1 = __builtin_amdgcn_readfirstlane(rowS[m+1]);
      int n2 = __builtin_amdgcn_readfirstlane(rowS[m+2]);
      int n3 = __builtin_amdgcn_readfirstlane(rowS[m+3]);
      float f0 = bf2f((unsigned short)u0), f1 = bf2f((unsigned short)(u0 >> 16));
      float f2v = bf2f((unsigned short)u1), f3 = bf2f((unsigned short)(u1 >> 16));
      if (n0 != cur) { atomicAdd(&agg[(size_t)cur * HD + c], s); s = 0.f; cur = n0; }
      s += f0;
      if (n1 != cur) { atomicAdd(&agg[(size_t)cur * HD + c], s); s = 0.f; cur = n1; }
      s += f1;
      if (n2 != cur) { atomicAdd(&agg[(size_t)cur * HD + c], s); s = 0.f; cur = n2; }
      s += f2v;
      if (n3 != cur) { atomicAdd(&agg[(size_t)cur * HD + c], s); s = 0.f; cur = n3; }
      s += f3;
    }
    atomicAdd(&agg[(size_t)cur * HD + c], s);
  }
}

// ---------------- launch ----------------
extern "C" void kernel_launch(void* const* d_in, const int* in_sizes, int n_in,
                              void* d_out, int out_size, void* d_ws, size_t ws_size,
                              hipStream_t stream)
{
  (void)in_sizes; (void)n_in; (void)out_size; (void)ws_size;
  const float* h_in  = (const float*)d_in[0];
  const int*   ei    = (const int*)d_in[1];
  const float* cd    = (const float*)d_in[2];
  const float* w_in  = (const float*)d_in[3];
  const float* b_in  = (const float*)d_in[4];
  const float* w_out = (const float*)d_in[5];
  const float* b_out = (const float*)d_in[6];
  const float* ew1   = (const float*)d_in[7];
  const float* eb1   = (const float*)d_in[8];
  const float* ew2   = (const float*)d_in[9];
  const float* eb2   = (const float*)d_in[10];
  const float* nw1   = (const float*)d_in[11];
  const float* nb1   = (const float*)d_in[12];
  const float* nw2   = (const float*)d_in[13];
  const float* nb2   = (const float*)d_in[14];
  float* out = (float*)d_out;

  char* base = (char*)d_ws;
  size_t off = 0;
  auto WS = [&](size_t bytes) -> char* {
    char* p = base + off;
    off = (off + bytes + 255) & ~(size_t)255;
    return p;
  };
  float*          radial  = (float*)WS((size_t)NE * 4);
  unsigned short* hb_in   = (unsigned short*)WS((size_t)NN * NF * 2);
  unsigned short* hcur    = (unsigned short*)WS((size_t)NN * HD * 2);
  float*          aggF    = (float*)WS((size_t)NN * HD * 4);
  unsigned short* hT      = (unsigned short*)WS((size_t)NN * HTS * 2);  // 25.6 MB bf16
  unsigned short* w_in_t  = (unsigned short*)WS((size_t)NF * HD * 2);
  unsigned short* w_out_t = (unsigned short*)WS((size_t)NF * HD * 2);
  unsigned short* ew1cat  = (unsigned short*)WS((size_t)NL * 512 * 256 * 2);
  float*          w1r     = (float*)WS((size_t)NL * HD * 4);
  float*          b1e     = (float*)WS((size_t)NL * 512 * 4);
  unsigned short* ew2t    = (unsigned short*)WS((size_t)NL * HD * HD * 2);
  unsigned short* nw1t    = (unsigned short*)WS((size_t)NL * HD * 512 * 2);
  unsigned short* nw2t    = (unsigned short*)WS((size_t)NL * HD * HD * 2);
  int*            hist    = (int*)WS((size_t)NN * 4);
  int*            starts  = (int*)WS((size_t)(NN + 1) * 4);
  int*            cursor  = (int*)WS((size_t)NN * 4);
  int*            rowcol  = (int*)WS((size_t)NE * 2 * 4);
  float*          radial_s= (float*)WS((size_t)NE * 4);

  hipMemsetAsync(hist, 0, (size_t)NN * 4, stream);
  hipMemsetAsync(aggF, 0, (size_t)NN * HD * 4, stream);
  prep_small<<<dim3(513, 19), 256, 0, stream>>>(w_in, w_out, ew1, ew2, nw1, nw2, eb1,
      w_in_t, w_out_t, ew1cat, w1r, b1e, ew2t, nw1t, nw2t);
  prep_big<<<dim3(5000, 2), 256, 0, stream>>>(h_in, cd, hb_in, radial);
  hist_k<<<NE / 256, 256, 0, stream>>>(ei, hist);
  scan_k<<<1, 256, 0, stream>>>(hist, starts, cursor);
  scatter_k<<<NE / 256, 256, 0, stream>>>(ei, ei + NE, radial, cursor, rowcol, radial_s);

  // h = h_in @ w_in + b_in
  gemm_k<<<dim3(157, 2), 256, 0, stream>>>(hb_in, w_in_t, b_in, hcur, nullptr,
      NN, HD, NF, NF, HD, 0);
  // layer-0 hT table (l>0 tables are produced by node_k phase C)
  gemm_k<<<dim3(157, 4), 256, 0, stream>>>(hcur, ew1cat, b1e, hT, nullptr,
      NN, 512, HD, HD, HTS, 0);

  for (int l = 0; l < NL; ++l) {
    edge_k<<<NE / 64, 256, 0, stream>>>(hT, rowcol, radial_s,
        w1r + l * HD, ew2t + (size_t)l * HD * HD, eb2 + l * HD, aggF);
    const int last = (l == NL - 1);
    node_k<<<(NN + 31) / 32, 256, 0, stream>>>(hcur, aggF,
        nw1t + (size_t)l * HD * 512, nb1 + l * HD,
        nw2t + (size_t)l * HD * HD, nb2 + l * HD,
        last ? nullptr : (ew1cat + (size_t)(l+1) * 512 * 256),
        last ? nullptr : (b1e + (size_t)(l+1) * 512),
        hT, NN);
  }

  // out = h @ w_out + b_out  (fp32 output)
  gemm_k<<<dim3(157, 1), 256, 0, stream>>>(hcur, w_out_t, b_out, nullptr, out,
      NN, NF, HD, HD, NF, 0);
}

// Round 7
// 1145.908 us; speedup vs baseline: 1.6911x; 1.0686x over previous
//
#include <hip/hip_runtime.h>
#include <hip/hip_bf16.h>
#include <cstdint>
#include <cstddef>

#define NN 20000
#define NE 640000
#define NF 64
#define HD 256
#define NL 4
#define HTS 640   // hT row stride in shorts: 1280 B = 5x256 B (destaggers HBM channels)

typedef __attribute__((ext_vector_type(8))) short short8;
typedef __attribute__((ext_vector_type(4))) float f32x4;
typedef __attribute__((ext_vector_type(2))) float f32x2;

__device__ __forceinline__ float bf2f(unsigned short u){
  union { unsigned int i; float f; } x; x.i = ((unsigned int)u) << 16; return x.f;
}
__device__ __forceinline__ unsigned short f2bf(float f){
  union { float f; unsigned int i; } x; x.f = f;
  unsigned int r = x.i + 0x7FFFu + ((x.i >> 16) & 1u);   // RNE
  return (unsigned short)(r >> 16);
}
// packed 2xf32 -> 2xbf16 (v_cvt_pk_bf16_f32 on gfx950, RNE)
__device__ __forceinline__ unsigned int pk2bf(float a, float b){
  union { __hip_bfloat162 h; unsigned int u; } cv;
  cv.h = __float22bfloat162_rn(float2{a, b});
  return cv.u;
}
// silu via guaranteed-native v_exp_f32 + v_rcp_f32
__device__ __forceinline__ float silu_f(float v){
  float e = __builtin_amdgcn_exp2f(v * -1.442695041f);
  return v * __builtin_amdgcn_rcpf(1.0f + e);
}
// packed silu on 2 lanes: pk mul/add around the 2 scalar trans ops
__device__ __forceinline__ f32x2 silu2(f32x2 v){
  f32x2 t = v * (f32x2){-1.442695041f, -1.442695041f};   // v_pk_mul_f32
  f32x2 e = (f32x2){__builtin_amdgcn_exp2f(t.x), __builtin_amdgcn_exp2f(t.y)};
  f32x2 d = e + (f32x2){1.0f, 1.0f};                      // v_pk_add_f32
  f32x2 r = (f32x2){__builtin_amdgcn_rcpf(d.x), __builtin_amdgcn_rcpf(d.y)};
  return v * r;                                           // v_pk_mul_f32
}
__device__ __forceinline__ void async16(const void* g, void* l){
  __builtin_amdgcn_global_load_lds(
      (const __attribute__((address_space(1))) unsigned int*)g,
      (__attribute__((address_space(3))) unsigned int*)l, 16, 0, 0);
}

// ---------------- prep_small: weight transposes -> bf16, b1e (513-block slices) -------
__global__ __launch_bounds__(256) void prep_small(
    const float* __restrict__ w_in, const float* __restrict__ w_out,
    const float* __restrict__ ew1, const float* __restrict__ ew2,
    const float* __restrict__ nw1, const float* __restrict__ nw2,
    const float* __restrict__ eb1,
    unsigned short* __restrict__ w_in_t, unsigned short* __restrict__ w_out_t,
    unsigned short* __restrict__ ew1cat, float* __restrict__ w1r,
    float* __restrict__ b1e,
    unsigned short* __restrict__ ew2t, unsigned short* __restrict__ nw1t,
    unsigned short* __restrict__ nw2t)
{
  const int s = blockIdx.y;
  const int tid = blockIdx.x * 256 + threadIdx.x;
  if (s == 18) {
    if (tid < NL * 512) {
      int l = tid >> 9, c = tid & 511;
      b1e[tid] = (c < 256) ? eb1[l * HD + c] : 0.0f;
    }
    return;
  }
  if (s >= 2 && s < 6) {
    int l = s - 2;
    if (tid >= 513 * HD) return;
    int k = tid / HD, n = tid - k * HD;
    float v = ew1[(size_t)l * 513 * HD + tid];
    if (k == 512) { w1r[l * HD + n] = v; return; }
    unsigned short* dst = ew1cat + (size_t)l * 512 * 256;
    if (k < 256) dst[(size_t)n * 256 + k] = f2bf(v);
    else         dst[(size_t)(256 + n) * 256 + (k - 256)] = f2bf(v);
    return;
  }
  const float* src; unsigned short* dst; int K, N;
  if (s == 0)      { src = w_in;  dst = w_in_t;  K = NF;   N = HD; }
  else if (s == 1) { src = w_out; dst = w_out_t; K = HD;   N = NF; }
  else if (s < 10) { int l = s-6;  src = ew2 + (size_t)l*HD*HD;   dst = ew2t + (size_t)l*HD*HD;  K = HD;   N = HD; }
  else if (s < 14) { int l = s-10; src = nw1 + (size_t)l*2*HD*HD; dst = nw1t + (size_t)l*HD*512; K = 2*HD; N = HD; }
  else             { int l = s-14; src = nw2 + (size_t)l*HD*HD;   dst = nw2t + (size_t)l*HD*HD;  K = HD;   N = HD; }
  if (tid >= K * N) return;
  int k = tid / N, n = tid - k * N;
  dst[(size_t)n * K + k] = f2bf(src[tid]);
}

// ---------------- prep_big: h->bf16, radial ----------------
__global__ __launch_bounds__(256) void prep_big(
    const float* __restrict__ h_in, const float* __restrict__ cd,
    unsigned short* __restrict__ hb_in, float* __restrict__ radial)
{
  const int s = blockIdx.y;
  const int tid = blockIdx.x * 256 + threadIdx.x;
  if (s == 0) {
    if (tid < NN * NF) hb_in[tid] = f2bf(h_in[tid]);
  } else {
    if (tid < NE) {
      float x = cd[tid*3+0], y = cd[tid*3+1], z = cd[tid*3+2];
      radial[tid] = x*x + y*y + z*z;
    }
  }
}

// ---------------- counting sort of edges by row ----------------
__global__ __launch_bounds__(256) void hist_k(const int* __restrict__ erow, int* __restrict__ hist){
  int e = blockIdx.x * 256 + threadIdx.x;
  if (e < NE){
    unsigned r = (unsigned)erow[e]; if (r >= NN) r = 0;
    atomicAdd(&hist[r], 1);
  }
}

__global__ __launch_bounds__(256) void scan_k(const int* __restrict__ hist,
                                              int* __restrict__ starts, int* __restrict__ cursor){
  __shared__ int part[256];
  const int t = threadIdx.x;
  const int CH = 79;
  int lo = t * CH, hi = lo + CH; if (hi > NN) hi = NN; if (lo > NN) lo = NN;
  int s = 0;
  for (int i = lo; i < hi; ++i) s += hist[i];
  part[t] = s; __syncthreads();
  for (int off = 1; off < 256; off <<= 1){
    int v = (t >= off) ? part[t - off] : 0;
    __syncthreads();
    part[t] += v;
    __syncthreads();
  }
  int base = (t == 0) ? 0 : part[t - 1];
  for (int i = lo; i < hi; ++i){ starts[i] = base; cursor[i] = base; base += hist[i]; }
  if (t == 255) starts[NN] = part[255];
}

// scatter materializes (row,col) pairs and re-sorted radial at the sorted slot
__global__ __launch_bounds__(256) void scatter_k(const int* __restrict__ erow,
                                                 const int* __restrict__ ecol,
                                                 const float* __restrict__ radial,
                                                 int* __restrict__ cursor,
                                                 int* __restrict__ rowcol,
                                                 float* __restrict__ radial_s){
  int e = blockIdx.x * 256 + threadIdx.x;
  if (e < NE){
    unsigned r = (unsigned)erow[e]; if (r >= NN) r = 0;
    unsigned c = (unsigned)ecol[e]; if (c >= NN) c = 0;
    int pos = atomicAdd(&cursor[r], 1);
    rowcol[2*pos]   = (int)r;
    rowcol[2*pos+1] = (int)c;
    radial_s[pos] = radial[e];
  }
}

// ---------------- node0_k: hcur = hb@w_in^T+b_in; hT = hcur@ew1cat0^T+b1e0 ----------
// 32-row strips (625 blocks); hcur strip kept in LDS between phases.
// Replaces the standalone gemm-in (K=64) and layer-0 hT GEMM.
__global__ __launch_bounds__(256, 4) void node0_k(
    const unsigned short* __restrict__ hb,      // [NN][64] bf16
    const unsigned short* __restrict__ w_in_t,  // [256][64]
    const float* __restrict__ b_in,
    const unsigned short* __restrict__ w1cat0,  // [512][256]
    const float* __restrict__ b1e0,             // [512]
    unsigned short* __restrict__ hcur,          // [NN][256] out
    unsigned short* __restrict__ hT,            // [NN][HTS] out
    int M)
{
  __shared__ __align__(16) unsigned short As[32*64];      // 4 KB
  __shared__ __align__(16) unsigned short Bs[256*32];     // 16 KB
  __shared__ __align__(16) unsigned short xL[8*32*32];    // 16 KB (hcur strip)
  const int t = threadIdx.x;
  const int lane = t & 63, wave = t >> 6;
  const int ln15 = lane & 15, q = lane >> 4;
  const int bm = blockIdx.x;
  const int sc = (t & 3) * 8;
  const int srB = t >> 2;              // 0..63

  float bvin[4];
  #pragma unroll
  for (int j = 0; j < 4; ++j) bvin[j] = b_in[wave*64 + j*16 + ln15];

  f32x4 acc[2][4];
  #pragma unroll
  for (int i = 0; i < 2; ++i)
    #pragma unroll
    for (int j = 0; j < 4; ++j) acc[i][j] = (f32x4){0.f,0.f,0.f,0.f};

  // stage A strip once: [32][64] bf16
  async16(hb + (size_t)(bm*32 + (t >> 3)) * NF + (t & 7)*8, &As[t*8]);

  // ---------- phase A: K = 64, hcur_strip = hb_strip @ w_in_t^T + b_in ----------
  for (int kt = 0; kt < 2; ++kt) {
    #pragma unroll
    for (int i = 0; i < 4; ++i)
      async16(w_in_t + (size_t)(i*64 + srB) * NF + kt*32 + sc, &Bs[i*2048 + t*8]);
    __syncthreads();
    short8 fa[2], fb[4];
    #pragma unroll
    for (int i = 0; i < 2; ++i) fa[i] = *(const short8*)&As[(i*16 + ln15)*64 + kt*32 + q*8];
    #pragma unroll
    for (int j = 0; j < 4; ++j) fb[j] = *(const short8*)&Bs[(wave*64 + j*16 + ln15)*32 + q*8];
    #pragma unroll
    for (int i = 0; i < 2; ++i)
      #pragma unroll
      for (int j = 0; j < 4; ++j)
        acc[i][j] = __builtin_amdgcn_mfma_f32_16x16x32_bf16(fa[i], fb[j], acc[i][j], 0, 0, 0);
    __syncthreads();
  }

  // epilogue A: hcur = acc + b_in (no silu) -> global + xL
  #pragma unroll
  for (int i = 0; i < 2; ++i) {
    #pragma unroll
    for (int j = 0; j < 4; ++j) {
      const int n = wave*64 + j*16 + ln15;
      const int kt2 = n >> 5, k31 = n & 31;
      const int r0 = i*16 + q*4;
      const int m0 = bm*32 + r0;
      #pragma unroll
      for (int r = 0; r < 4; ++r) {
        unsigned short h = f2bf(acc[i][j][r] + bvin[j]);
        hcur[(size_t)(m0 + r) * HD + n] = h;
        xL[kt2*1024 + (r0 + r)*32 + k31] = h;
      }
    }
  }

  // ---------- phase C: hT strip = hcur_strip @ w1cat0^T + b1e0 ----------
  #pragma unroll
  for (int half = 0; half < 2; ++half) {
    #pragma unroll
    for (int i = 0; i < 2; ++i)
      #pragma unroll
      for (int j = 0; j < 4; ++j) acc[i][j] = (f32x4){0.f,0.f,0.f,0.f};
    for (int kt2 = 0; kt2 < 8; ++kt2) {
      #pragma unroll
      for (int i = 0; i < 4; ++i)
        async16(w1cat0 + (size_t)(half*256 + i*64 + srB) * 256 + kt2*32 + sc,
                &Bs[i*2048 + t*8]);
      __syncthreads();
      short8 fa[2], fb[4];
      #pragma unroll
      for (int i = 0; i < 2; ++i) fa[i] = *(const short8*)&xL[kt2*1024 + (i*16 + ln15)*32 + q*8];
      #pragma unroll
      for (int j = 0; j < 4; ++j) fb[j] = *(const short8*)&Bs[(wave*64 + j*16 + ln15)*32 + q*8];
      #pragma unroll
      for (int i = 0; i < 2; ++i)
        #pragma unroll
        for (int j = 0; j < 4; ++j)
          acc[i][j] = __builtin_amdgcn_mfma_f32_16x16x32_bf16(fa[i], fb[j], acc[i][j], 0, 0, 0);
      __syncthreads();
    }
    #pragma unroll
    for (int i = 0; i < 2; ++i) {
      #pragma unroll
      for (int j = 0; j < 4; ++j) {
        const int n = half*256 + wave*64 + j*16 + ln15;
        const float bv = b1e0[n];
        #pragma unroll
        for (int r = 0; r < 4; ++r) {
          const int m = bm*32 + i*16 + q*4 + r;
          hT[(size_t)m * HTS + n] = f2bf(acc[i][j][r] + bv);
        }
      }
    }
  }
  (void)M;
}

// ---------------- fused node MLP + next-layer hT (or final projection) ----------------
// 32-row strips (625 blocks).
// A: x1 = silu([hcur|bf16(agg)] @ W1^T + b1)   (x1 in LDS only; agg strip zeroed)
// B: hcur = x1 @ W2^T + b2                     (in-place; strip also kept in LDS)
// C: hT = hcur_strip @ ew1cat_next^T + b1e_next   (layers 0..NL-2)
// D: out = hcur_strip @ w_out^T + b_out, fp32     (last layer; replaces final GEMM)
__global__ __launch_bounds__(256, 4) void node_k(
    unsigned short* __restrict__ hcur,      // [NN][256] bf16, read (k<256) + write
    float* __restrict__ aggF,               // [NN][256] fp32, read (k>=256) + zero
    const unsigned short* __restrict__ w1t, // [256][512]
    const float* __restrict__ b1,
    const unsigned short* __restrict__ w2t, // [256][256]
    const float* __restrict__ b2,
    const unsigned short* __restrict__ w1cat_next, // [512][256] or null
    const float* __restrict__ b1e_next,            // [512] or null
    unsigned short* __restrict__ hT,               // [NN][HTS] out (if w1cat_next)
    const unsigned short* __restrict__ w_out_t,    // [64][256] (used if last)
    const float* __restrict__ b_out,               // [64]
    float* __restrict__ outF,                      // [NN][64] fp32 (used if last)
    int M)
{
  __shared__ __align__(16) unsigned short As[32*32];      // 2 KB
  __shared__ __align__(16) unsigned short Bs[256*32];     // 16 KB
  __shared__ __align__(16) unsigned short xL[8*32*32];    // 16 KB (x1, then hcur strip)
  const int t = threadIdx.x;
  const int lane = t & 63, wave = t >> 6;
  const int ln15 = lane & 15, q = lane >> 4;
  const int bm = blockIdx.x;
  const int sc = (t & 3) * 8;
  const int srA = (t & 127) >> 2;      // 0..31 (A staging, threads 0..127)
  const int srB = t >> 2;              // 0..63 (B staging rows)

  const int rowA = bm*32 + srA;
  const unsigned short* aSrc = hcur + (size_t)rowA * HD + sc;
  float* gSrc = aggF + (size_t)rowA * HD + sc;

  float bv1[4], bv2[4];
  #pragma unroll
  for (int j = 0; j < 4; ++j) {
    bv1[j] = b1[wave*64 + j*16 + ln15];
    bv2[j] = b2[wave*64 + j*16 + ln15];
  }

  f32x4 acc[2][4];
  #pragma unroll
  for (int i = 0; i < 2; ++i)
    #pragma unroll
    for (int j = 0; j < 4; ++j) acc[i][j] = (f32x4){0.f,0.f,0.f,0.f};

  // ---------- phase A: K = 512 over [hcur | bf16(aggF)] ----------
  for (int kt = 0; kt < 16; ++kt) {
    if (t < 128) {
      if (kt < 8) {
        async16(aSrc + kt*32, &As[t*8]);
      } else {
        float* p = gSrc + (kt-8)*32;
        float4 a0 = *(const float4*)p;
        float4 a1 = *(const float4*)(p + 4);
        union { unsigned int u[4]; short8 s8; } cv;
        cv.u[0] = pk2bf(a0.x, a0.y); cv.u[1] = pk2bf(a0.z, a0.w);
        cv.u[2] = pk2bf(a1.x, a1.y); cv.u[3] = pk2bf(a1.z, a1.w);
        // zero the strip for next layer's edge_k
        *(float4*)p = float4{0.f,0.f,0.f,0.f};
        *(float4*)(p + 4) = float4{0.f,0.f,0.f,0.f};
        *(short8*)&As[t*8] = cv.s8;
      }
    }
    #pragma unroll
    for (int i = 0; i < 4; ++i)
      async16(w1t + (size_t)(i*64 + srB) * 512 + kt*32 + sc, &Bs[i*2048 + t*8]);
    __syncthreads();
    short8 fa[2], fb[4];
    #pragma unroll
    for (int i = 0; i < 2; ++i) fa[i] = *(const short8*)&As[(i*16 + ln15)*32 + q*8];
    #pragma unroll
    for (int j = 0; j < 4; ++j) fb[j] = *(const short8*)&Bs[(wave*64 + j*16 + ln15)*32 + q*8];
    #pragma unroll
    for (int i = 0; i < 2; ++i)
      #pragma unroll
      for (int j = 0; j < 4; ++j)
        acc[i][j] = __builtin_amdgcn_mfma_f32_16x16x32_bf16(fa[i], fb[j], acc[i][j], 0, 0, 0);
    __syncthreads();
  }

  // x1 = silu(acc + b1) -> xL (kt2-blocked: [kt2][row][k&31])
  #pragma unroll
  for (int i = 0; i < 2; ++i) {
    #pragma unroll
    for (int j = 0; j < 4; ++j) {
      const int k = wave*64 + j*16 + ln15;
      const int kt2 = k >> 5, k31 = k & 31;
      const f32x2 bb = (f32x2){bv1[j], bv1[j]};
      f32x2 s01 = (f32x2){acc[i][j][0], acc[i][j][1]} + bb;
      f32x2 s23 = (f32x2){acc[i][j][2], acc[i][j][3]} + bb;
      f32x2 r01 = silu2(s01);
      f32x2 r23 = silu2(s23);
      const int r0 = i*16 + q*4;
      xL[kt2*1024 + (r0  )*32 + k31] = f2bf(r01.x);
      xL[kt2*1024 + (r0+1)*32 + k31] = f2bf(r01.y);
      xL[kt2*1024 + (r0+2)*32 + k31] = f2bf(r23.x);
      xL[kt2*1024 + (r0+3)*32 + k31] = f2bf(r23.y);
    }
  }
  #pragma unroll
  for (int i = 0; i < 2; ++i)
    #pragma unroll
    for (int j = 0; j < 4; ++j) acc[i][j] = (f32x4){0.f,0.f,0.f,0.f};

  // ---------- phase B: K = 256, A = x1 (LDS), B = W2t ----------
  for (int kt2 = 0; kt2 < 8; ++kt2) {
    #pragma unroll
    for (int i = 0; i < 4; ++i)
      async16(w2t + (size_t)(i*64 + srB) * 256 + kt2*32 + sc, &Bs[i*2048 + t*8]);
    __syncthreads();
    short8 fa[2], fb[4];
    #pragma unroll
    for (int i = 0; i < 2; ++i) fa[i] = *(const short8*)&xL[kt2*1024 + (i*16 + ln15)*32 + q*8];
    #pragma unroll
    for (int j = 0; j < 4; ++j) fb[j] = *(const short8*)&Bs[(wave*64 + j*16 + ln15)*32 + q*8];
    #pragma unroll
    for (int i = 0; i < 2; ++i)
      #pragma unroll
      for (int j = 0; j < 4; ++j)
        acc[i][j] = __builtin_amdgcn_mfma_f32_16x16x32_bf16(fa[i], fb[j], acc[i][j], 0, 0, 0);
    __syncthreads();
  }

  // epilogue B: hcur = acc + b2 (no silu) -> global, AND strip -> xL for phase C/D
  #pragma unroll
  for (int i = 0; i < 2; ++i) {
    #pragma unroll
    for (int j = 0; j < 4; ++j) {
      const int n = wave*64 + j*16 + ln15;
      const int kt2 = n >> 5, k31 = n & 31;
      const int r0 = i*16 + q*4;
      const int m0 = bm*32 + r0;
      #pragma unroll
      for (int r = 0; r < 4; ++r) {
        unsigned short h = f2bf(acc[i][j][r] + bv2[j]);
        hcur[(size_t)(m0 + r) * HD + n] = h;
        xL[kt2*1024 + (r0 + r)*32 + k31] = h;
      }
    }
  }

  if (w1cat_next) {
    // ---------- phase C: hT strip = hcur_strip @ ew1cat_next^T + b1e_next ----------
    #pragma unroll
    for (int half = 0; half < 2; ++half) {
      #pragma unroll
      for (int i = 0; i < 2; ++i)
        #pragma unroll
        for (int j = 0; j < 4; ++j) acc[i][j] = (f32x4){0.f,0.f,0.f,0.f};
      for (int kt2 = 0; kt2 < 8; ++kt2) {
        #pragma unroll
        for (int i = 0; i < 4; ++i)
          async16(w1cat_next + (size_t)(half*256 + i*64 + srB) * 256 + kt2*32 + sc,
                  &Bs[i*2048 + t*8]);
        __syncthreads();
        short8 fa[2], fb[4];
        #pragma unroll
        for (int i = 0; i < 2; ++i) fa[i] = *(const short8*)&xL[kt2*1024 + (i*16 + ln15)*32 + q*8];
        #pragma unroll
        for (int j = 0; j < 4; ++j) fb[j] = *(const short8*)&Bs[(wave*64 + j*16 + ln15)*32 + q*8];
        #pragma unroll
        for (int i = 0; i < 2; ++i)
          #pragma unroll
          for (int j = 0; j < 4; ++j)
            acc[i][j] = __builtin_amdgcn_mfma_f32_16x16x32_bf16(fa[i], fb[j], acc[i][j], 0, 0, 0);
        __syncthreads();
      }
      #pragma unroll
      for (int i = 0; i < 2; ++i) {
        #pragma unroll
        for (int j = 0; j < 4; ++j) {
          const int n = half*256 + wave*64 + j*16 + ln15;
          const float bv = b1e_next[n];
          #pragma unroll
          for (int r = 0; r < 4; ++r) {
            const int m = bm*32 + i*16 + q*4 + r;
            hT[(size_t)m * HTS + n] = f2bf(acc[i][j][r] + bv);
          }
        }
      }
    }
  } else {
    // ---------- phase D: out = hcur_strip @ w_out^T + b_out (N=64, fp32) ----------
    const int nD = wave*16 + ln15;             // 0..63
    const float bvD = b_out[nD];
    f32x4 accD[2];
    accD[0] = (f32x4){0.f,0.f,0.f,0.f};
    accD[1] = (f32x4){0.f,0.f,0.f,0.f};
    for (int kt2 = 0; kt2 < 8; ++kt2) {
      // stage w_out_t rows 0..63, k-slice kt2*32 (one async16 per thread)
      async16(w_out_t + (size_t)srB * 256 + kt2*32 + sc, &Bs[t*8]);
      __syncthreads();
      short8 fa[2], fb;
      #pragma unroll
      for (int i = 0; i < 2; ++i) fa[i] = *(const short8*)&xL[kt2*1024 + (i*16 + ln15)*32 + q*8];
      fb = *(const short8*)&Bs[nD*32 + q*8];
      #pragma unroll
      for (int i = 0; i < 2; ++i)
        accD[i] = __builtin_amdgcn_mfma_f32_16x16x32_bf16(fa[i], fb, accD[i], 0, 0, 0);
      __syncthreads();
    }
    #pragma unroll
    for (int i = 0; i < 2; ++i) {
      #pragma unroll
      for (int r = 0; r < 4; ++r) {
        const int m = bm*32 + i*16 + q*4 + r;
        outF[(size_t)m * NF + nD] = accD[i][r] + bvD;
      }
    }
  }
  (void)M;
}

// ---------------- fused edge MLP + aggregation (bf16 hT, stride-640 destagger) --------
__global__ __launch_bounds__(256, 4) void edge_k(
    const unsigned short* __restrict__ hT,   // [NN][HTS] bf16, cols 0..511 valid
    const int* __restrict__ rowcol,          // [NE][2] sorted (row,col)
    const float* __restrict__ radial_s,      // [NE] sorted radial
    const float* __restrict__ w1r,           // [256]
    const unsigned short* __restrict__ w2t,  // [256][256]
    const float* __restrict__ b2,
    float* __restrict__ agg)                  // [NN][256] fp32, pre-zeroed
{
  __shared__ __align__(16) unsigned short MBUF[16896];   // 33.8 KB
  __shared__ int   rowS[64];
  __shared__ float w1rS[256];
  unsigned short* M1  = MBUF;
  unsigned short* m2T = MBUF;

  const int t = threadIdx.x;
  const int lane = t & 63, wave = t >> 6;
  const int ln15 = lane & 15, q = lane >> 4;
  // chunked XCD swizzle: XCD k owns a contiguous 1/8 of sorted-edge space (hr L2 reuse)
  int blk = blockIdx.x;
  blk = (blk & 7) * ((int)gridDim.x >> 3) + (blk >> 3);
  const int e0 = blk * 64;
  const int sr = t >> 2;
  const int sc_swz = (((t & 3) ^ ((sr >> 1) & 3))) * 8;
  const int xq = ((q ^ ((ln15 >> 1) & 3))) * 8;

  // early small loads (before the 16 gathers: vmcnt retires in issue order)
  const int2 rc = *(const int2*)(rowcol + 2*(e0 + sr));   // gather base (1 load)
  int rowv = 0;
  if (t < 64) rowv = rowcol[2*(e0 + t)];
  const float w1v = w1r[t];
  const float rad = radial_s[e0 + sr];

  float bv2[4];
  #pragma unroll
  for (int j = 0; j < 4; ++j) bv2[j] = b2[wave*64 + j*16 + ln15];

  const unsigned short* hr = hT + (size_t)rc.x * HTS + sc_swz;
  const unsigned short* hc = hT + (size_t)rc.y * HTS + 256 + sc_swz;

  // batch all 16 gather b128s into registers, interleaved
  short8 va[8], vb[8];
  #pragma unroll
  for (int ch = 0; ch < 8; ++ch) {
    va[ch] = *(const short8*)(hr + ch*32);
    vb[ch] = *(const short8*)(hc + ch*32);
  }

  if (t < 64) rowS[t] = rowv;
  w1rS[t] = w1v;

  const unsigned short* w2row[4];
  #pragma unroll
  for (int j = 0; j < 4; ++j)
    w2row[j] = w2t + (size_t)(wave*64 + j*16 + ln15) * HD + q*8;

  __syncthreads();

  // prologue: m1 = silu(hr + hc + rad*w1r) -> M1 (kt-blocked, swizzled), b128 stores
  const f32x2 rad2 = (f32x2){rad, rad};
  #pragma unroll
  for (int ch = 0; ch < 8; ++ch) {
    const int c0 = ch*32 + sc_swz;
    const unsigned int* ua = (const unsigned int*)&va[ch];
    const unsigned int* ub = (const unsigned int*)&vb[ch];
    union { unsigned int u[4]; short8 s; } res;
    #pragma unroll
    for (int i = 0; i < 4; ++i) {
      union { unsigned int i; float f; } alo, ahi, blo, bhi;
      alo.i = ua[i] << 16; ahi.i = ua[i] & 0xFFFF0000u;
      blo.i = ub[i] << 16; bhi.i = ub[i] & 0xFFFF0000u;
      f32x2 av = (f32x2){alo.f, ahi.f};
      f32x2 bv = (f32x2){blo.f, bhi.f};
      f32x2 wv = *(const f32x2*)&w1rS[c0 + 2*i];
      f32x2 o = av + bv;
      o = o + rad2 * wv;            // pk fma
      f32x2 sv = silu2(o);
      res.u[i] = pk2bf(sv.x, sv.y);
    }
    *(short8*)&M1[ch*2048 + sr*32 + (t & 3)*8] = res.s;
  }
  __syncthreads();

  // phase 2: K = 256 (M1 @ W2^T); fb direct from global (L2-resident w2t)
  f32x4 acc2[4][4];
  #pragma unroll
  for (int i = 0; i < 4; ++i)
    #pragma unroll
    for (int j = 0; j < 4; ++j) acc2[i][j] = (f32x4){0.f,0.f,0.f,0.f};

  __builtin_amdgcn_s_setprio(1);
  #pragma unroll
  for (int kt = 0; kt < 8; ++kt) {
    short8 fa[4], fb[4];
    #pragma unroll
    for (int j = 0; j < 4; ++j) fb[j] = *(const short8*)(w2row[j] + kt*32);
    #pragma unroll
    for (int i = 0; i < 4; ++i) fa[i] = *(const short8*)&M1[kt*2048 + (i*16 + ln15)*32 + xq];
    #pragma unroll
    for (int i = 0; i < 4; ++i)
      #pragma unroll
      for (int j = 0; j < 4; ++j)
        acc2[i][j] = __builtin_amdgcn_mfma_f32_16x16x32_bf16(fa[i], fb[j], acc2[i][j], 0, 0, 0);
  }
  __builtin_amdgcn_s_setprio(0);
  __syncthreads();

  // epilogue 2a: silu -> m2T[col][stride 66] in LDS (pk math)
  #pragma unroll
  for (int i = 0; i < 4; ++i) {
    #pragma unroll
    for (int j = 0; j < 4; ++j) {
      const int n = wave*64 + j*16 + ln15;
      const f32x2 b2v = (f32x2){bv2[j], bv2[j]};
      f32x2 s01 = (f32x2){acc2[i][j][0], acc2[i][j][1]} + b2v;
      f32x2 s23 = (f32x2){acc2[i][j][2], acc2[i][j][3]} + b2v;
      f32x2 r01 = silu2(s01);
      f32x2 r23 = silu2(s23);
      const int m = i*16 + q*4;
      *(unsigned int*)&m2T[n*66 + m]     = pk2bf(r01.x, r01.y);
      *(unsigned int*)&m2T[n*66 + m + 2] = pk2bf(r23.x, r23.y);
    }
  }
  __syncthreads();

  // epilogue 2b: per-column segmented reduction (rowS readfirstlane -> scalar cmps)
  {
    const int c = t;
    int cur = __builtin_amdgcn_readfirstlane(rowS[0]);
    float s = 0.f;
    #pragma unroll
    for (int m = 0; m < 64; m += 4) {
      unsigned int u0 = *(const unsigned int*)&m2T[c*66 + m];
      unsigned int u1 = *(const unsigned int*)&m2T[c*66 + m + 2];
      int n0 = __builtin_amdgcn_readfirstlane(rowS[m]);
      int n1 = __builtin_amdgcn_readfirstlane(rowS[m+1]);
      int n2 = __builtin_amdgcn_readfirstlane(rowS[m+2]);
      int n3 = __builtin_amdgcn_readfirstlane(rowS[m+3]);
      float f0 = bf2f((unsigned short)u0), f1 = bf2f((unsigned short)(u0 >> 16));
      float f2v = bf2f((unsigned short)u1), f3 = bf2f((unsigned short)(u1 >> 16));
      if (n0 != cur) { atomicAdd(&agg[(size_t)cur * HD + c], s); s = 0.f; cur = n0; }
      s += f0;
      if (n1 != cur) { atomicAdd(&agg[(size_t)cur * HD + c], s); s = 0.f; cur = n1; }
      s += f1;
      if (n2 != cur) { atomicAdd(&agg[(size_t)cur * HD + c], s); s = 0.f; cur = n2; }
      s += f2v;
      if (n3 != cur) { atomicAdd(&agg[(size_t)cur * HD + c], s); s = 0.f; cur = n3; }
      s += f3;
    }
    atomicAdd(&agg[(size_t)cur * HD + c], s);
  }
}

// ---------------- launch ----------------
extern "C" void kernel_launch(void* const* d_in, const int* in_sizes, int n_in,
                              void* d_out, int out_size, void* d_ws, size_t ws_size,
                              hipStream_t stream)
{
  (void)in_sizes; (void)n_in; (void)out_size; (void)ws_size;
  const float* h_in  = (const float*)d_in[0];
  const int*   ei    = (const int*)d_in[1];
  const float* cd    = (const float*)d_in[2];
  const float* w_in  = (const float*)d_in[3];
  const float* b_in  = (const float*)d_in[4];
  const float* w_out = (const float*)d_in[5];
  const float* b_out = (const float*)d_in[6];
  const float* ew1   = (const float*)d_in[7];
  const float* eb1   = (const float*)d_in[8];
  const float* ew2   = (const float*)d_in[9];
  const float* eb2   = (const float*)d_in[10];
  const float* nw1   = (const float*)d_in[11];
  const float* nb1   = (const float*)d_in[12];
  const float* nw2   = (const float*)d_in[13];
  const float* nb2   = (const float*)d_in[14];
  float* out = (float*)d_out;

  char* base = (char*)d_ws;
  size_t off = 0;
  auto WS = [&](size_t bytes) -> char* {
    char* p = base + off;
    off = (off + bytes + 255) & ~(size_t)255;
    return p;
  };
  float*          radial  = (float*)WS((size_t)NE * 4);
  unsigned short* hb_in   = (unsigned short*)WS((size_t)NN * NF * 2);
  unsigned short* hcur    = (unsigned short*)WS((size_t)NN * HD * 2);
  float*          aggF    = (float*)WS((size_t)NN * HD * 4);
  unsigned short* hT      = (unsigned short*)WS((size_t)NN * HTS * 2);  // 25.6 MB bf16
  unsigned short* w_in_t  = (unsigned short*)WS((size_t)NF * HD * 2);
  unsigned short* w_out_t = (unsigned short*)WS((size_t)NF * HD * 2);
  unsigned short* ew1cat  = (unsigned short*)WS((size_t)NL * 512 * 256 * 2);
  float*          w1r     = (float*)WS((size_t)NL * HD * 4);
  float*          b1e     = (float*)WS((size_t)NL * 512 * 4);
  unsigned short* ew2t    = (unsigned short*)WS((size_t)NL * HD * HD * 2);
  unsigned short* nw1t    = (unsigned short*)WS((size_t)NL * HD * 512 * 2);
  unsigned short* nw2t    = (unsigned short*)WS((size_t)NL * HD * HD * 2);
  int*            hist    = (int*)WS((size_t)NN * 4);
  int*            starts  = (int*)WS((size_t)(NN + 1) * 4);
  int*            cursor  = (int*)WS((size_t)NN * 4);
  int*            rowcol  = (int*)WS((size_t)NE * 2 * 4);
  float*          radial_s= (float*)WS((size_t)NE * 4);

  hipMemsetAsync(hist, 0, (size_t)NN * 4, stream);
  hipMemsetAsync(aggF, 0, (size_t)NN * HD * 4, stream);
  prep_small<<<dim3(513, 19), 256, 0, stream>>>(w_in, w_out, ew1, ew2, nw1, nw2, eb1,
      w_in_t, w_out_t, ew1cat, w1r, b1e, ew2t, nw1t, nw2t);
  prep_big<<<dim3(5000, 2), 256, 0, stream>>>(h_in, cd, hb_in, radial);
  hist_k<<<NE / 256, 256, 0, stream>>>(ei, hist);
  scan_k<<<1, 256, 0, stream>>>(hist, starts, cursor);
  scatter_k<<<NE / 256, 256, 0, stream>>>(ei, ei + NE, radial, cursor, rowcol, radial_s);

  // embedding + layer-0 hT table, fused per 32-row strip
  node0_k<<<NN / 32, 256, 0, stream>>>(hb_in, w_in_t, b_in, ew1cat, b1e, hcur, hT, NN);

  for (int l = 0; l < NL; ++l) {
    edge_k<<<NE / 64, 256, 0, stream>>>(hT, rowcol, radial_s,
        w1r + l * HD, ew2t + (size_t)l * HD * HD, eb2 + l * HD, aggF);
    const int last = (l == NL - 1);
    node_k<<<NN / 32, 256, 0, stream>>>(hcur, aggF,
        nw1t + (size_t)l * HD * 512, nb1 + l * HD,
        nw2t + (size_t)l * HD * HD, nb2 + l * HD,
        last ? nullptr : (ew1cat + (size_t)(l+1) * 512 * 256),
        last ? nullptr : (b1e + (size_t)(l+1) * 512),
        hT, w_out_t, b_out, out, NN);
  }
}